// Round 1
// 588.424 us; speedup vs baseline: 1.0031x; 1.0031x over previous
//
#include <hip/hip_runtime.h>
#include <math.h>

#define Hh 720
#define Ww 1280
#define Bb 2
#define HW (Hh*Ww)
#define OUTC 18
#define EPSF 1e-7f

// Ownership-tiled splat. Each block OWNS an OWN_W x OWN_H output region
// (exact tiling, no halo in LDS). It processes the extended source region
// (OWN_W+5 x OWN_H+5) of pixels whose bilinear footprint can reach the owned
// region (|dx|,|dy| <= DMAX => corner targets in [src-2, src+3]). Corners
// falling outside the owned region are dropped -- the neighboring block that
// owns them also processes that source. Every output pixel is therefore
// written by exactly ONE block => flush is plain stores, no global atomics.
// Far-flow sources (|d| > DMAX, P ~ 1e-4) are applied by far_prepass_kernel
// with global atomics BEFORE the splat, which also flags affected tiles so
// only those tiles pay a read-add flush.
#define DMAX 2.0f
#define OWN_W 32
#define OWN_H 8
#define SRC_W (OWN_W + 5)        // 37
#define SRC_H (OWN_H + 5)        // 13
#define NSRC (SRC_W * SRC_H)     // 481
#define TILES_X (Ww / OWN_W)     // 40
#define TILES_Y (Hh / OWN_H)     // 90
#define NTILES (Bb * TILES_X * TILES_Y)

// ---------------------------------------------------------------------------
// Rare-path: sources with |0.5*flow| > DMAX splat directly to global with
// atomics (acc planes are pre-zeroed). Flags the target tiles in `flags` so
// the splat flush knows to read-add there. Runs BEFORE splat_tile_kernel.
// ---------------------------------------------------------------------------
__global__ __launch_bounds__(256) void far_prepass_kernel(
    const float* __restrict__ img0, const float* __restrict__ img1,
    const float* __restrict__ flow0, const float* __restrict__ flow1,
    const float* __restrict__ z0, const float* __restrict__ z1,
    float* __restrict__ out, int* __restrict__ flags)
{
    int i = blockIdx.x * 256 + threadIdx.x;
    if (i >= Bb * HW) return;
    int b = i / HW;
    int p = i - b * HW;
    int y = p / Ww;
    int x = p - y * Ww;

    for (int d = 0; d < 2; ++d) {
        const float* flw = d ? flow0 : flow1;
        float dx = 0.5f * flw[((size_t)b * 2 + 1) * HW + p];  // x-disp = flow ch1
        float dy = 0.5f * flw[((size_t)b * 2 + 0) * HW + p];  // y-disp = flow ch0
        if (fabsf(dx) <= DMAX && fabsf(dy) <= DMAX) continue; // local: splat kernel handles

        const float* img = d ? img1 : img0;
        const float* met = d ? z0 : z1;
        float fx = (float)x + dx;
        float fy = (float)y + dy;
        float w  = expf(met[(size_t)b * HW + p]);
        float v0 = img[((size_t)b * 3 + 0) * HW + p] * w;
        float v1 = img[((size_t)b * 3 + 1) * HW + p] * w;
        float v2 = img[((size_t)b * 3 + 2) * HW + p] * w;

        float x0f = floorf(fx), y0f = floorf(fy);
        float x1f = x0f + 1.0f, y1f = y0f + 1.0f;
        int   x0  = (int)x0f,  y0i = (int)y0f;
        float wxs[2] = { x1f - fx, fx - x0f };
        float wys[2] = { y1f - fy, fy - y0f };

        float* accImg = out + ((size_t)b * OUTC + (d ? 9 : 6)) * HW;
        float* accW   = out + ((size_t)b * OUTC + (d ? 17 : 16)) * HW;

        for (int cy = 0; cy < 2; ++cy) {
            int yy = y0i + cy;
            if (yy < 0 || yy >= Hh) continue;
            for (int cx = 0; cx < 2; ++cx) {
                int xx = x0 + cx;
                if (xx < 0 || xx >= Ww) continue;
                float wt = wxs[cx] * wys[cy];
                if (wt == 0.0f) continue;
                int q = yy * Ww + xx;
                atomicAdd(accImg + q,          v0 * wt);
                atomicAdd(accImg + HW + q,     v1 * wt);
                atomicAdd(accImg + 2 * HW + q, v2 * wt);
                atomicAdd(accW + q,            w  * wt);
                if (flags)
                    flags[(b * TILES_Y + yy / OWN_H) * TILES_X + xx / OWN_W] = 1;
            }
        }
    }
}

// ---------------------------------------------------------------------------
// Ownership-tiled bidirectional splat. Flush is plain stores (read-add only
// for tiles flagged by the prepass) and writes NORMALIZED img channels to
// ch6..11 plus raw weight sums to ch16/17 (erode needs the raw sums; fuse
// consumes ch6..11 directly without dividing).
// ---------------------------------------------------------------------------
__global__ __launch_bounds__(256) void splat_tile_kernel(
    const float* __restrict__ img0, const float* __restrict__ img1,
    const float* __restrict__ flow0, const float* __restrict__ flow1,
    const float* __restrict__ z0, const float* __restrict__ z1,
    float* __restrict__ out, const int* __restrict__ flags)
{
    __shared__ float acc[2][4][OWN_H][OWN_W];   // [dir][ch: v0,v1,v2,w][y][x]

    float* af = &acc[0][0][0][0];
    for (int c = threadIdx.x; c < 2 * 4 * OWN_H * OWN_W; c += 256) af[c] = 0.0f;
    __syncthreads();

    const int tX0 = blockIdx.x * OWN_W;
    const int tY0 = blockIdx.y * OWN_H;
    const int b   = blockIdx.z;

    for (int s = threadIdx.x; s < NSRC; s += 256) {
        int syl = s / SRC_W;
        int sxl = s - syl * SRC_W;
        int sx = tX0 + sxl - 3;   // source x in [tX0-3, tX0+OWN_W+2]
        int sy = tY0 + syl - 3;   // source y in [tY0-3, tY0+OWN_H+2]
        if (sx < 0 || sx >= Ww || sy < 0 || sy >= Hh) continue;
        int p = sy * Ww + sx;

        for (int d = 0; d < 2; ++d) {
            const float* flw = d ? flow0 : flow1;
            float dx = 0.5f * flw[((size_t)b * 2 + 1) * HW + p];
            float dy = 0.5f * flw[((size_t)b * 2 + 0) * HW + p];
            if (!(fabsf(dx) <= DMAX && fabsf(dy) <= DMAX)) continue; // prepass handled

            const float* img = d ? img1 : img0;
            const float* met = d ? z0 : z1;
            float fx = (float)sx + dx;
            float fy = (float)sy + dy;
            float w  = expf(met[(size_t)b * HW + p]);
            float v0 = img[((size_t)b * 3 + 0) * HW + p] * w;
            float v1 = img[((size_t)b * 3 + 1) * HW + p] * w;
            float v2 = img[((size_t)b * 3 + 2) * HW + p] * w;

            float x0f = floorf(fx), y0f = floorf(fy);
            float x1f = x0f + 1.0f, y1f = y0f + 1.0f;
            int   x0  = (int)x0f,  y0i = (int)y0f;
            float wxs[2] = { x1f - fx, fx - x0f };
            float wys[2] = { y1f - fy, fy - y0f };

#pragma unroll
            for (int cy = 0; cy < 2; ++cy) {
                int ly = y0i + cy - tY0;
                if (ly < 0 || ly >= OWN_H) continue;   // not ours (or out of image)
#pragma unroll
                for (int cx = 0; cx < 2; ++cx) {
                    int lx = x0 + cx - tX0;
                    if (lx < 0 || lx >= OWN_W) continue;
                    float wt = wxs[cx] * wys[cy];
                    if (wt == 0.0f) continue;
                    atomicAdd(&acc[d][0][ly][lx], v0 * wt);
                    atomicAdd(&acc[d][1][ly][lx], v1 * wt);
                    atomicAdd(&acc[d][2][ly][lx], v2 * wt);
                    atomicAdd(&acc[d][3][ly][lx], w  * wt);
                }
            }
        }
    }
    __syncthreads();

    // flush: each thread owns exactly one output pixel -> plain stores.
    const int lx = threadIdx.x % OWN_W;
    const int ly = threadIdx.x / OWN_W;
    const size_t q = (size_t)(tY0 + ly) * Ww + (tX0 + lx);
    bool flagged = true;
    if (flags)
        flagged = flags[(b * TILES_Y + blockIdx.y) * TILES_X + blockIdx.x] != 0;

#pragma unroll
    for (int d = 0; d < 2; ++d) {
        float* accImg = out + ((size_t)b * OUTC + (d ? 9 : 6)) * HW;
        float* accW   = out + ((size_t)b * OUTC + (d ? 17 : 16)) * HW;
        float s0 = acc[d][0][ly][lx];
        float s1 = acc[d][1][ly][lx];
        float s2 = acc[d][2][ly][lx];
        float sw = acc[d][3][ly][lx];
        if (flagged) {            // rare: merge prepass far contributions
            s0 += accImg[q];
            s1 += accImg[HW + q];
            s2 += accImg[2 * HW + q];
            sw += accW[q];
        }
        float inv = 1.0f / (sw + EPSF);
        accImg[q]          = s0 * inv;   // normalized f01i / f10i
        accImg[HW + q]     = s1 * inv;
        accImg[2 * HW + q] = s2 * inv;
        accW[q]            = sw;         // raw weight sum for erode
    }
}

// ---------------------------------------------------------------------------
// Full-2D erosion of raw weight sums: ch16/17 -> ch12/13.
// morph_open(s/(s+eps)) == f(morph_open(s)) since x/(x+eps) is monotone.
// ---------------------------------------------------------------------------
__global__ __launch_bounds__(256) void erode_kernel(float* __restrict__ out,
                                                    const int* __restrict__ kptr)
{
    int i = blockIdx.x * 256 + threadIdx.x;
    if (i >= Bb * HW) return;
    int b = i / HW;
    int p = i - b * HW;
    int y = p / Ww;
    int x = p - y * Ww;
    int k = *kptr;

    const float* s01 = out + ((size_t)b * OUTC + 16) * HW;
    const float* s10 = out + ((size_t)b * OUTC + 17) * HW;
    float* er01 = out + ((size_t)b * OUTC + 12) * HW;
    float* er10 = out + ((size_t)b * OUTC + 13) * HW;

    if (k <= 0) { er01[p] = s01[p]; er10[p] = s10[p]; return; }

    int lo = (k - 1) / 2, hi = (k - 1) - lo;
    float m0 = INFINITY, m1 = INFINITY;
    for (int dy = -lo; dy <= hi; ++dy) {
        int yy = y + dy;
        if (yy < 0 || yy >= Hh) continue;
        for (int dx = -lo; dx <= hi; ++dx) {
            int xx = x + dx;
            if (xx < 0 || xx >= Ww) continue;
            int q = yy * Ww + xx;
            m0 = fminf(m0, s01[q]);
            m1 = fminf(m1, s10[q]);
        }
    }
    er01[p] = m0;
    er10[p] = m1;
}

// ---------------------------------------------------------------------------
// Fuse: dilate ch12/13 -> opened weight sum; mask = o/(o+eps); blend the
// already-normalized ch6..11. Writes ch0..5, 16, 17 only.
// ---------------------------------------------------------------------------
__global__ __launch_bounds__(256) void fuse_kernel(float* __restrict__ out,
                                                   const int* __restrict__ kptr)
{
    int i = blockIdx.x * 256 + threadIdx.x;
    if (i >= Bb * HW) return;
    int b = i / HW;
    int p = i - b * HW;
    int y = p / Ww;
    int x = p - y * Ww;
    int k = *kptr;

    const float* er01 = out + ((size_t)b * OUTC + 12) * HW;
    const float* er10 = out + ((size_t)b * OUTC + 13) * HW;

    float o0, o1;
    if (k <= 0) {
        o0 = er01[p];
        o1 = er10[p];
    } else {
        int lo = (k - 1) / 2, hi = (k - 1) - lo;
        o0 = -INFINITY; o1 = -INFINITY;
        for (int dy = -lo; dy <= hi; ++dy) {
            int yy = y + dy;
            if (yy < 0 || yy >= Hh) continue;
            for (int dx = -lo; dx <= hi; ++dx) {
                int xx = x + dx;
                if (xx < 0 || xx >= Ww) continue;
                int q = yy * Ww + xx;
                o0 = fmaxf(o0, er01[q]);
                o1 = fmaxf(o1, er10[q]);
            }
        }
    }

    float m01 = o0 / (o0 + EPSF);
    float m10 = o1 / (o1 + EPSF);

    float* ob = out + (size_t)b * OUTC * HW;
#pragma unroll
    for (int c = 0; c < 3; ++c) {
        float f01i = ob[((size_t)6 + c) * HW + p];   // already normalized by splat
        float f10i = ob[((size_t)9 + c) * HW + p];
        ob[((size_t)0 + c) * HW + p] = m01 * f01i + (1.0f - m01) * f10i;
        ob[((size_t)3 + c) * HW + p] = m10 * f10i + (1.0f - m10) * f01i;
    }
    ob[(size_t)16 * HW + p] = m01;
    ob[(size_t)17 * HW + p] = m10;
}

// ---------------------------------------------------------------------------
// Write scaled flows into ch12..15 (overwrites the parked erosions). Last.
// ---------------------------------------------------------------------------
__global__ __launch_bounds__(256) void flow_kernel(const float* __restrict__ flow0,
                                                   const float* __restrict__ flow1,
                                                   float* __restrict__ out)
{
    int i = blockIdx.x * 256 + threadIdx.x;
    if (i >= Bb * 4 * HW) return;
    int b = i / (4 * HW);
    int r = i - b * 4 * HW;
    int c = r / HW;
    int p = r - c * HW;
    float v = (c < 2) ? 0.5f * flow0[((size_t)b * 2 + c) * HW + p]
                      : 0.5f * flow1[((size_t)b * 2 + (c - 2)) * HW + p];
    out[((size_t)b * OUTC + 12 + c) * HW + p] = v;
}

extern "C" void kernel_launch(void* const* d_in, const int* in_sizes, int n_in,
                              void* d_out, int out_size, void* d_ws, size_t ws_size,
                              hipStream_t stream) {
    const float* img0  = (const float*)d_in[0];
    const float* img1  = (const float*)d_in[1];
    const float* flow0 = (const float*)d_in[2];
    const float* flow1 = (const float*)d_in[3];
    const float* z0    = (const float*)d_in[4];
    const float* z1    = (const float*)d_in[5];
    const int*   kptr  = (const int*)d_in[6];
    float* out = (float*)d_out;

    // zero the 8 accumulator planes (ch6..11 contiguous, ch16..17 contiguous)
    for (int b = 0; b < Bb; ++b) {
        hipMemsetAsync(out + ((size_t)b * OUTC + 6) * HW, 0, (size_t)6 * HW * sizeof(float), stream);
        hipMemsetAsync(out + ((size_t)b * OUTC + 16) * HW, 0, (size_t)2 * HW * sizeof(float), stream);
    }

    int* flags = nullptr;
    if (d_ws && ws_size >= (size_t)NTILES * sizeof(int)) {
        flags = (int*)d_ws;
        hipMemsetAsync(flags, 0, (size_t)NTILES * sizeof(int), stream);
    }

    int n = Bb * HW;
    int blocks = (n + 255) / 256;

    far_prepass_kernel<<<blocks, 256, 0, stream>>>(img0, img1, flow0, flow1, z0, z1, out, flags);

    dim3 sgrid(TILES_X, TILES_Y, Bb);   // 40 x 90 x 2
    splat_tile_kernel<<<sgrid, 256, 0, stream>>>(img0, img1, flow0, flow1, z0, z1, out, flags);
    erode_kernel<<<blocks, 256, 0, stream>>>(out, kptr);
    fuse_kernel<<<blocks, 256, 0, stream>>>(out, kptr);
    int n4 = Bb * 4 * HW;
    flow_kernel<<<(n4 + 255) / 256, 256, 0, stream>>>(flow0, flow1, out);
}

// Round 2
// 561.559 us; speedup vs baseline: 1.0511x; 1.0478x over previous
//
#include <hip/hip_runtime.h>
#include <math.h>

#define Hh 720
#define Ww 1280
#define Bb 2
#define HW (Hh*Ww)
#define OUTC 18
#define EPSF 1e-7f

// Ownership-tiled splat (R1 structure, R2 latency restructure).
// Each block OWNS an OWN_W x OWN_H output region (no halo in LDS) and scans
// the extended source region that can reach it; corners outside the owned
// region are dropped (the owning neighbor processes that source too). Flush
// is plain stores. Far-flow sources (|0.5*flow| > DMAX, P~1e-4) are handled
// by far_prepass_kernel with global atomics + per-tile flags.
// R2 changes: (a) all 12 plane loads per source are issued unconditionally
// up-front for 2 sources/thread -> 24 independent loads in flight (the R1
// kernel had VGPR=12 and a serial load->branch->load chain: latency-bound);
// (b) XCD-bijective block swizzle so halo re-reads hit the same XCD's L2.
#define DMAX 2.0f
#define OWN_W 32
#define OWN_H 8
#define SRC_W (OWN_W + 5)        // 37
#define SRC_H (OWN_H + 5)        // 13
#define NSRC (SRC_W * SRC_H)     // 481
#define TILES_X (Ww / OWN_W)     // 40
#define TILES_Y (Hh / OWN_H)     // 90
#define NTILES (Bb * TILES_X * TILES_Y)   // 7200 (divisible by 8)

// ---------------------------------------------------------------------------
// Rare-path: sources with |0.5*flow| > DMAX splat directly to global with
// atomics (acc planes pre-zeroed) and flag the target tiles. Runs first.
// ---------------------------------------------------------------------------
__global__ __launch_bounds__(256) void far_prepass_kernel(
    const float* __restrict__ img0, const float* __restrict__ img1,
    const float* __restrict__ flow0, const float* __restrict__ flow1,
    const float* __restrict__ z0, const float* __restrict__ z1,
    float* __restrict__ out, int* __restrict__ flags)
{
    int i = blockIdx.x * 256 + threadIdx.x;
    if (i >= Bb * HW) return;
    int b = i / HW;
    int p = i - b * HW;
    int y = p / Ww;
    int x = p - y * Ww;

    for (int d = 0; d < 2; ++d) {
        const float* flw = d ? flow0 : flow1;
        float dx = 0.5f * flw[((size_t)b * 2 + 1) * HW + p];  // x-disp = flow ch1
        float dy = 0.5f * flw[((size_t)b * 2 + 0) * HW + p];  // y-disp = flow ch0
        if (fabsf(dx) <= DMAX && fabsf(dy) <= DMAX) continue; // local: splat handles

        const float* img = d ? img1 : img0;
        const float* met = d ? z0 : z1;
        float fx = (float)x + dx;
        float fy = (float)y + dy;
        float w  = expf(met[(size_t)b * HW + p]);
        float v0 = img[((size_t)b * 3 + 0) * HW + p] * w;
        float v1 = img[((size_t)b * 3 + 1) * HW + p] * w;
        float v2 = img[((size_t)b * 3 + 2) * HW + p] * w;

        float x0f = floorf(fx), y0f = floorf(fy);
        float x1f = x0f + 1.0f, y1f = y0f + 1.0f;
        int   x0  = (int)x0f,  y0i = (int)y0f;
        float wxs[2] = { x1f - fx, fx - x0f };
        float wys[2] = { y1f - fy, fy - y0f };

        float* accImg = out + ((size_t)b * OUTC + (d ? 9 : 6)) * HW;
        float* accW   = out + ((size_t)b * OUTC + (d ? 17 : 16)) * HW;

        for (int cy = 0; cy < 2; ++cy) {
            int yy = y0i + cy;
            if (yy < 0 || yy >= Hh) continue;
            for (int cx = 0; cx < 2; ++cx) {
                int xx = x0 + cx;
                if (xx < 0 || xx >= Ww) continue;
                float wt = wxs[cx] * wys[cy];
                if (wt == 0.0f) continue;
                int q = yy * Ww + xx;
                atomicAdd(accImg + q,          v0 * wt);
                atomicAdd(accImg + HW + q,     v1 * wt);
                atomicAdd(accImg + 2 * HW + q, v2 * wt);
                atomicAdd(accW + q,            w  * wt);
                if (flags)
                    flags[(b * TILES_Y + yy / OWN_H) * TILES_X + xx / OWN_W] = 1;
            }
        }
    }
}

// ---------------------------------------------------------------------------
// Splat. 1D grid of NTILES blocks, XCD-bijective swizzle inside.
// ---------------------------------------------------------------------------
__global__ __launch_bounds__(256) void splat_tile_kernel(
    const float* __restrict__ img0, const float* __restrict__ img1,
    const float* __restrict__ flow0, const float* __restrict__ flow1,
    const float* __restrict__ z0, const float* __restrict__ z1,
    float* __restrict__ out, const int* __restrict__ flags)
{
    __shared__ float acc[2][4][OWN_H][OWN_W];   // [dir][ch: v0,v1,v2,w][y][x]

    float* af = &acc[0][0][0][0];
    for (int c = threadIdx.x; c < 2 * 4 * OWN_H * OWN_W; c += 256) af[c] = 0.0f;

    // XCD-aware bijective swizzle: NTILES % 8 == 0, chunk = NTILES/8 = 900.
    // Each XCD gets a contiguous run of tiles (tx-fastest) -> halo L2 reuse.
    int wg   = blockIdx.x;
    int wgid = (wg & 7) * (NTILES / 8) + (wg >> 3);
    int b    = wgid / (TILES_X * TILES_Y);
    int rr   = wgid - b * TILES_X * TILES_Y;
    int tY   = rr / TILES_X;
    int tX   = rr - tY * TILES_X;
    const int tX0 = tX * OWN_W;
    const int tY0 = tY * OWN_H;

    __syncthreads();

    // ---- issue ALL loads for this thread's (up to) 2 sources up-front ----
    float Lf1x[2], Lf1y[2], Lf0x[2], Lf0y[2], Lz0[2], Lz1[2];
    float Li0[2][3], Li1[2][3];
    bool  Lv[2];
    int   Lsx[2], Lsy[2];

#pragma unroll
    for (int it = 0; it < 2; ++it) {
        int s = threadIdx.x + it * 256;
        bool v = (s < NSRC);
        if (s > NSRC - 1) s = NSRC - 1;
        int syl = s / SRC_W;
        int sxl = s - syl * SRC_W;
        int sx = tX0 + sxl - 3;   // source x in [tX0-3, tX0+OWN_W+2]
        int sy = tY0 + syl - 3;
        v = v && (sx >= 0) && (sx < Ww) && (sy >= 0) && (sy < Hh);
        int sxc = min(max(sx, 0), Ww - 1);
        int syc = min(max(sy, 0), Hh - 1);
        int p = syc * Ww + sxc;

        Lf1x[it] = flow1[((size_t)b * 2 + 1) * HW + p];
        Lf1y[it] = flow1[((size_t)b * 2 + 0) * HW + p];
        Lf0x[it] = flow0[((size_t)b * 2 + 1) * HW + p];
        Lf0y[it] = flow0[((size_t)b * 2 + 0) * HW + p];
        Lz1[it]  = z1[(size_t)b * HW + p];
        Lz0[it]  = z0[(size_t)b * HW + p];
#pragma unroll
        for (int c = 0; c < 3; ++c) {
            Li0[it][c] = img0[((size_t)b * 3 + c) * HW + p];
            Li1[it][c] = img1[((size_t)b * 3 + c) * HW + p];
        }
        Lv[it] = v; Lsx[it] = sx; Lsy[it] = sy;
    }

    // ---- splat from registers ----
#pragma unroll
    for (int it = 0; it < 2; ++it) {
        if (!Lv[it]) continue;
        float w1 = expf(Lz1[it]);
        float w0 = expf(Lz0[it]);
#pragma unroll
        for (int d = 0; d < 2; ++d) {
            float dx = 0.5f * (d ? Lf0x[it] : Lf1x[it]);
            float dy = 0.5f * (d ? Lf0y[it] : Lf1y[it]);
            if (!(fabsf(dx) <= DMAX && fabsf(dy) <= DMAX)) continue; // prepass handled

            float w  = d ? w0 : w1;
            float v0 = (d ? Li1[it][0] : Li0[it][0]) * w;
            float v1 = (d ? Li1[it][1] : Li0[it][1]) * w;
            float v2 = (d ? Li1[it][2] : Li0[it][2]) * w;

            float fx = (float)Lsx[it] + dx;
            float fy = (float)Lsy[it] + dy;
            float x0f = floorf(fx), y0f = floorf(fy);
            float x1f = x0f + 1.0f, y1f = y0f + 1.0f;
            int   x0  = (int)x0f,  y0i = (int)y0f;
            float wxs[2] = { x1f - fx, fx - x0f };
            float wys[2] = { y1f - fy, fy - y0f };

#pragma unroll
            for (int cy = 0; cy < 2; ++cy) {
                int ly = y0i + cy - tY0;
                if (ly < 0 || ly >= OWN_H) continue;   // not ours (or out of image)
#pragma unroll
                for (int cx = 0; cx < 2; ++cx) {
                    int lx = x0 + cx - tX0;
                    if (lx < 0 || lx >= OWN_W) continue;
                    float wt = wxs[cx] * wys[cy];
                    if (wt == 0.0f) continue;
                    atomicAdd(&acc[d][0][ly][lx], v0 * wt);
                    atomicAdd(&acc[d][1][ly][lx], v1 * wt);
                    atomicAdd(&acc[d][2][ly][lx], v2 * wt);
                    atomicAdd(&acc[d][3][ly][lx], w  * wt);
                }
            }
        }
    }
    __syncthreads();

    // flush: each thread owns exactly one output pixel -> plain stores.
    const int lx = threadIdx.x % OWN_W;
    const int ly = threadIdx.x / OWN_W;
    const size_t q = (size_t)(tY0 + ly) * Ww + (tX0 + lx);
    bool flagged = true;
    if (flags)
        flagged = flags[(b * TILES_Y + tY) * TILES_X + tX] != 0;

#pragma unroll
    for (int d = 0; d < 2; ++d) {
        float* accImg = out + ((size_t)b * OUTC + (d ? 9 : 6)) * HW;
        float* accW   = out + ((size_t)b * OUTC + (d ? 17 : 16)) * HW;
        float s0 = acc[d][0][ly][lx];
        float s1 = acc[d][1][ly][lx];
        float s2 = acc[d][2][ly][lx];
        float sw = acc[d][3][ly][lx];
        if (flagged) {            // rare: merge prepass far contributions
            s0 += accImg[q];
            s1 += accImg[HW + q];
            s2 += accImg[2 * HW + q];
            sw += accW[q];
        }
        float inv = 1.0f / (sw + EPSF);
        accImg[q]          = s0 * inv;   // normalized f01i / f10i
        accImg[HW + q]     = s1 * inv;
        accImg[2 * HW + q] = s2 * inv;
        accW[q]            = sw;         // raw weight sum for erode
    }
}

// ---------------------------------------------------------------------------
// Full-2D erosion of raw weight sums: ch16/17 -> ch12/13.
// k==5 fast path: fully unrolled, coordinate-clamped (exact for min with
// SAME + inf padding: clamped duplicates are valid pixels, min unchanged).
// ---------------------------------------------------------------------------
__global__ __launch_bounds__(256) void erode_kernel(float* __restrict__ out,
                                                    const int* __restrict__ kptr)
{
    int i = blockIdx.x * 256 + threadIdx.x;
    if (i >= Bb * HW) return;
    int b = i / HW;
    int p = i - b * HW;
    int y = p / Ww;
    int x = p - y * Ww;
    int k = *kptr;

    const float* s01 = out + ((size_t)b * OUTC + 16) * HW;
    const float* s10 = out + ((size_t)b * OUTC + 17) * HW;
    float* er01 = out + ((size_t)b * OUTC + 12) * HW;
    float* er10 = out + ((size_t)b * OUTC + 13) * HW;

    if (k <= 0) { er01[p] = s01[p]; er10[p] = s10[p]; return; }

    float m0 = INFINITY, m1 = INFINITY;
    if (k == 5) {
#pragma unroll
        for (int dy = -2; dy <= 2; ++dy) {
            int yy = min(max(y + dy, 0), Hh - 1);
#pragma unroll
            for (int dx = -2; dx <= 2; ++dx) {
                int xx = min(max(x + dx, 0), Ww - 1);
                int q = yy * Ww + xx;
                m0 = fminf(m0, s01[q]);
                m1 = fminf(m1, s10[q]);
            }
        }
    } else {
        int lo = (k - 1) / 2, hi = (k - 1) - lo;
        for (int dy = -lo; dy <= hi; ++dy) {
            int yy = y + dy;
            if (yy < 0 || yy >= Hh) continue;
            for (int dx = -lo; dx <= hi; ++dx) {
                int xx = x + dx;
                if (xx < 0 || xx >= Ww) continue;
                int q = yy * Ww + xx;
                m0 = fminf(m0, s01[q]);
                m1 = fminf(m1, s10[q]);
            }
        }
    }
    er01[p] = m0;
    er10[p] = m1;
}

// ---------------------------------------------------------------------------
// Fuse: dilate ch12/13 (k==5 fast path, clamped -- exact for max with SAME +
// -inf padding); mask = o/(o+eps); blend already-normalized ch6..11.
// Writes ch0..5, 16, 17.
// ---------------------------------------------------------------------------
__global__ __launch_bounds__(256) void fuse_kernel(float* __restrict__ out,
                                                   const int* __restrict__ kptr)
{
    int i = blockIdx.x * 256 + threadIdx.x;
    if (i >= Bb * HW) return;
    int b = i / HW;
    int p = i - b * HW;
    int y = p / Ww;
    int x = p - y * Ww;
    int k = *kptr;

    const float* er01 = out + ((size_t)b * OUTC + 12) * HW;
    const float* er10 = out + ((size_t)b * OUTC + 13) * HW;

    float o0, o1;
    if (k <= 0) {
        o0 = er01[p];
        o1 = er10[p];
    } else if (k == 5) {
        o0 = -INFINITY; o1 = -INFINITY;
#pragma unroll
        for (int dy = -2; dy <= 2; ++dy) {
            int yy = min(max(y + dy, 0), Hh - 1);
#pragma unroll
            for (int dx = -2; dx <= 2; ++dx) {
                int xx = min(max(x + dx, 0), Ww - 1);
                int q = yy * Ww + xx;
                o0 = fmaxf(o0, er01[q]);
                o1 = fmaxf(o1, er10[q]);
            }
        }
    } else {
        int lo = (k - 1) / 2, hi = (k - 1) - lo;
        o0 = -INFINITY; o1 = -INFINITY;
        for (int dy = -lo; dy <= hi; ++dy) {
            int yy = y + dy;
            if (yy < 0 || yy >= Hh) continue;
            for (int dx = -lo; dx <= hi; ++dx) {
                int xx = x + dx;
                if (xx < 0 || xx >= Ww) continue;
                int q = yy * Ww + xx;
                o0 = fmaxf(o0, er01[q]);
                o1 = fmaxf(o1, er10[q]);
            }
        }
    }

    float m01 = o0 / (o0 + EPSF);
    float m10 = o1 / (o1 + EPSF);

    float* ob = out + (size_t)b * OUTC * HW;
#pragma unroll
    for (int c = 0; c < 3; ++c) {
        float f01i = ob[((size_t)6 + c) * HW + p];   // already normalized by splat
        float f10i = ob[((size_t)9 + c) * HW + p];
        ob[((size_t)0 + c) * HW + p] = m01 * f01i + (1.0f - m01) * f10i;
        ob[((size_t)3 + c) * HW + p] = m10 * f10i + (1.0f - m10) * f01i;
    }
    ob[(size_t)16 * HW + p] = m01;
    ob[(size_t)17 * HW + p] = m10;
}

// ---------------------------------------------------------------------------
// Write scaled flows into ch12..15 (overwrites the parked erosions). Last.
// ---------------------------------------------------------------------------
__global__ __launch_bounds__(256) void flow_kernel(const float* __restrict__ flow0,
                                                   const float* __restrict__ flow1,
                                                   float* __restrict__ out)
{
    int i = blockIdx.x * 256 + threadIdx.x;
    if (i >= Bb * 4 * HW) return;
    int b = i / (4 * HW);
    int r = i - b * 4 * HW;
    int c = r / HW;
    int p = r - c * HW;
    float v = (c < 2) ? 0.5f * flow0[((size_t)b * 2 + c) * HW + p]
                      : 0.5f * flow1[((size_t)b * 2 + (c - 2)) * HW + p];
    out[((size_t)b * OUTC + 12 + c) * HW + p] = v;
}

extern "C" void kernel_launch(void* const* d_in, const int* in_sizes, int n_in,
                              void* d_out, int out_size, void* d_ws, size_t ws_size,
                              hipStream_t stream) {
    const float* img0  = (const float*)d_in[0];
    const float* img1  = (const float*)d_in[1];
    const float* flow0 = (const float*)d_in[2];
    const float* flow1 = (const float*)d_in[3];
    const float* z0    = (const float*)d_in[4];
    const float* z1    = (const float*)d_in[5];
    const int*   kptr  = (const int*)d_in[6];
    float* out = (float*)d_out;

    // zero the 8 accumulator planes (ch6..11 contiguous, ch16..17 contiguous)
    for (int b = 0; b < Bb; ++b) {
        hipMemsetAsync(out + ((size_t)b * OUTC + 6) * HW, 0, (size_t)6 * HW * sizeof(float), stream);
        hipMemsetAsync(out + ((size_t)b * OUTC + 16) * HW, 0, (size_t)2 * HW * sizeof(float), stream);
    }

    int* flags = nullptr;
    if (d_ws && ws_size >= (size_t)NTILES * sizeof(int)) {
        flags = (int*)d_ws;
        hipMemsetAsync(flags, 0, (size_t)NTILES * sizeof(int), stream);
    }

    int n = Bb * HW;
    int blocks = (n + 255) / 256;

    far_prepass_kernel<<<blocks, 256, 0, stream>>>(img0, img1, flow0, flow1, z0, z1, out, flags);

    splat_tile_kernel<<<NTILES, 256, 0, stream>>>(img0, img1, flow0, flow1, z0, z1, out, flags);
    erode_kernel<<<blocks, 256, 0, stream>>>(out, kptr);
    fuse_kernel<<<blocks, 256, 0, stream>>>(out, kptr);
    int n4 = Bb * 4 * HW;
    flow_kernel<<<(n4 + 255) / 256, 256, 0, stream>>>(flow0, flow1, out);
}

// Round 4
// 315.840 us; speedup vs baseline: 1.8689x; 1.7780x over previous
//
#include <hip/hip_runtime.h>
#include <math.h>

#define Hh 720
#define Ww 1280
#define Bb 2
#define HW (Hh*Ww)
#define OUTC 18
#define EPSF 1e-7f

// R4: GATHER softsplat with REFERENCE-EXACT weight arithmetic.
// R3's gather computed hat weights as 1-|dx+u| (small-magnitude, exact);
// the reference computes fx = x + 0.5*flow at magnitude ~1e3 (ULP ~1e-4),
// floors THAT, and derives corner weights from it. Knife-edge support-set
// differences flipped post-morph-open mask pixels (absmax 1.0). R4 stages
// the reference-rounded decomposition {off=floor(fx)-sx, frac=fx-floor(fx)}
// (both Sterbenz-exact) so every corner weight is bit-identical to the
// reference scatter; only the add order differs (proven tolerable in R2).
// Hot path has ZERO atomics (LDS or global): each block owns a 32x8 output
// tile; each thread accumulates its own pixel in registers over the 6x6
// candidate source window staged in LDS. Far sources (|0.5*flow| > DMAX,
// P~1e-4) are applied by far_prepass_kernel with global atomics + per-tile
// flags; flagged tiles merge in the flush.
#define DMAX 2.0f
#define OWN_W 32
#define OWN_H 8
#define SRC_W (OWN_W + 5)        // 37
#define SRC_H (OWN_H + 5)        // 13
#define NSRC (SRC_W * SRC_H)     // 481
#define TILES_X (Ww / OWN_W)     // 40
#define TILES_Y (Hh / OWN_H)     // 90
#define NTILES (Bb * TILES_X * TILES_Y)   // 7200 (divisible by 8)

// ---------------------------------------------------------------------------
// Rare-path: sources with |0.5*flow| > DMAX splat directly to global with
// atomics (acc planes pre-zeroed) and flag the target tiles. Runs first.
// Also writes ch14/15 = 0.5*flow1 (it already loads flow1).
// Uses the same fx = x + dx arithmetic as the reference (R2-proven).
// ---------------------------------------------------------------------------
__global__ __launch_bounds__(256) void far_prepass_kernel(
    const float* __restrict__ img0, const float* __restrict__ img1,
    const float* __restrict__ flow0, const float* __restrict__ flow1,
    const float* __restrict__ z0, const float* __restrict__ z1,
    float* __restrict__ out, int* __restrict__ flags)
{
    int i = blockIdx.x * 256 + threadIdx.x;
    if (i >= Bb * HW) return;
    int b = i / HW;
    int p = i - b * HW;
    int y = p / Ww;
    int x = p - y * Ww;

    float f1x = flow1[((size_t)b * 2 + 1) * HW + p];
    float f1y = flow1[((size_t)b * 2 + 0) * HW + p];
    float f0x = flow0[((size_t)b * 2 + 1) * HW + p];
    float f0y = flow0[((size_t)b * 2 + 0) * HW + p];
    float dxs[2] = { 0.5f * f1x, 0.5f * f0x };   // d=0: flow1, d=1: flow0
    float dys[2] = { 0.5f * f1y, 0.5f * f0y };

    // ch14 = 0.5*flow1[ch0], ch15 = 0.5*flow1[ch1]
    out[((size_t)b * OUTC + 14) * HW + p] = 0.5f * f1y;
    out[((size_t)b * OUTC + 15) * HW + p] = 0.5f * f1x;

    for (int d = 0; d < 2; ++d) {
        float dx = dxs[d], dy = dys[d];
        if (fabsf(dx) <= DMAX && fabsf(dy) <= DMAX) continue; // local: gather handles

        const float* img = d ? img1 : img0;
        const float* met = d ? z0 : z1;
        float fx = (float)x + dx;
        float fy = (float)y + dy;
        float w  = expf(met[(size_t)b * HW + p]);
        float v0 = img[((size_t)b * 3 + 0) * HW + p] * w;
        float v1 = img[((size_t)b * 3 + 1) * HW + p] * w;
        float v2 = img[((size_t)b * 3 + 2) * HW + p] * w;

        float x0f = floorf(fx), y0f = floorf(fy);
        float x1f = x0f + 1.0f, y1f = y0f + 1.0f;
        int   x0  = (int)x0f,  y0i = (int)y0f;
        float wxs[2] = { x1f - fx, fx - x0f };
        float wys[2] = { y1f - fy, fy - y0f };

        float* accImg = out + ((size_t)b * OUTC + (d ? 9 : 6)) * HW;
        float* accW   = out + ((size_t)b * OUTC + (d ? 17 : 16)) * HW;

        for (int cy = 0; cy < 2; ++cy) {
            int yy = y0i + cy;
            if (yy < 0 || yy >= Hh) continue;
            for (int cx = 0; cx < 2; ++cx) {
                int xx = x0 + cx;
                if (xx < 0 || xx >= Ww) continue;
                float wt = wxs[cx] * wys[cy];
                if (wt == 0.0f) continue;
                int q = yy * Ww + xx;
                atomicAdd(accImg + q,          v0 * wt);
                atomicAdd(accImg + HW + q,     v1 * wt);
                atomicAdd(accImg + 2 * HW + q, v2 * wt);
                atomicAdd(accW + q,            w  * wt);
                if (flags)
                    flags[(b * TILES_Y + yy / OWN_H) * TILES_X + xx / OWN_W] = 1;
            }
        }
    }
}

// ---------------------------------------------------------------------------
// Gather splat. 1D grid of NTILES blocks, XCD-bijective swizzle inside.
// ---------------------------------------------------------------------------
__global__ __launch_bounds__(256) void gather_splat_kernel(
    const float* __restrict__ img0, const float* __restrict__ img1,
    const float* __restrict__ flow0, const float* __restrict__ flow1,
    const float* __restrict__ z0, const float* __restrict__ z1,
    float* __restrict__ out, const int* __restrict__ flags)
{
    __shared__ float4 geo[2][SRC_H][SRC_W];  // {offx, offy, fracx, fracy}; off=1e9 if dead
    __shared__ float4 vw [2][SRC_H][SRC_W];  // {v0*w, v1*w, v2*w, w}

    // XCD-aware bijective swizzle (NTILES % 8 == 0): contiguous tile runs per XCD.
    int wg   = blockIdx.x;
    int wgid = (wg & 7) * (NTILES / 8) + (wg >> 3);
    int b    = wgid / (TILES_X * TILES_Y);
    int rr   = wgid - b * (TILES_X * TILES_Y);
    int tY   = rr / TILES_X;
    int tX   = rr - tY * TILES_X;
    const int tX0 = tX * OWN_W;
    const int tY0 = tY * OWN_H;

    // ---- stage the source window (plain LDS writes, every cell written) ----
    for (int c = threadIdx.x; c < NSRC; c += 256) {
        int cy = c / SRC_W, cx = c - cy * SRC_W;
        int sx = tX0 + cx - 2;
        int sy = tY0 + cy - 2;
        bool inimg = (sx >= 0) && (sx < Ww) && (sy >= 0) && (sy < Hh);
        int p = min(max(sy, 0), Hh - 1) * Ww + min(max(sx, 0), Ww - 1);

        float f1x = flow1[((size_t)b * 2 + 1) * HW + p];
        float f1y = flow1[((size_t)b * 2 + 0) * HW + p];
        float f0x = flow0[((size_t)b * 2 + 1) * HW + p];
        float f0y = flow0[((size_t)b * 2 + 0) * HW + p];
        float zz1 = z1[(size_t)b * HW + p];
        float zz0 = z0[(size_t)b * HW + p];
        float a0 = img0[((size_t)b * 3 + 0) * HW + p];
        float a1 = img0[((size_t)b * 3 + 1) * HW + p];
        float a2 = img0[((size_t)b * 3 + 2) * HW + p];
        float c0 = img1[((size_t)b * 3 + 0) * HW + p];
        float c1 = img1[((size_t)b * 3 + 1) * HW + p];
        float c2 = img1[((size_t)b * 3 + 2) * HW + p];

        float dx0 = 0.5f * f1x, dy0 = 0.5f * f1y;   // dir0: img0 by 0.5*flow1
        float dx1 = 0.5f * f0x, dy1 = 0.5f * f0y;   // dir1: img1 by 0.5*flow0
        bool l0 = inimg && (fabsf(dx0) <= DMAX) && (fabsf(dy0) <= DMAX);
        bool l1 = inimg && (fabsf(dx1) <= DMAX) && (fabsf(dy1) <= DMAX);
        float w0 = l0 ? expf(zz1) : 0.0f;
        float w1 = l1 ? expf(zz0) : 0.0f;

        // reference-rounded decomposition (bit-exact weights):
        //   fx = (float)sx + dx  (same rounding as gx + flow*0.5 in the ref)
        //   frac = fx - floor(fx)  and  1-frac == floor(fx)+1-fx  (both exact)
        float fx0 = (float)sx + dx0, fy0 = (float)sy + dy0;
        float fx1 = (float)sx + dx1, fy1 = (float)sy + dy1;
        float x0f0 = floorf(fx0), y0f0 = floorf(fy0);
        float x0f1 = floorf(fx1), y0f1 = floorf(fy1);

        geo[0][cy][cx] = make_float4(l0 ? x0f0 - (float)sx : 1e9f,
                                     l0 ? y0f0 - (float)sy : 1e9f,
                                     fx0 - x0f0, fy0 - y0f0);
        geo[1][cy][cx] = make_float4(l1 ? x0f1 - (float)sx : 1e9f,
                                     l1 ? y0f1 - (float)sy : 1e9f,
                                     fx1 - x0f1, fy1 - y0f1);
        vw[0][cy][cx] = make_float4(a0 * w0, a1 * w0, a2 * w0, w0);
        vw[1][cy][cx] = make_float4(c0 * w1, c1 * w1, c2 * w1, w1);
    }
    __syncthreads();

    // ---- gather: register accumulation over the 6x6 candidate offsets ----
    const int qlx = threadIdx.x & (OWN_W - 1);
    const int qly = threadIdx.x >> 5;

    float acc[2][4];
#pragma unroll
    for (int d = 0; d < 2; ++d)
#pragma unroll
        for (int c = 0; c < 4; ++c) acc[d][c] = 0.0f;

#pragma unroll
    for (int d = 0; d < 2; ++d) {
#pragma unroll
        for (int oy = 0; oy < 6; ++oy) {
            const float oyf = (float)(oy - 2);     // u_y = sy - qy
#pragma unroll
            for (int ox = 0; ox < 6; ++ox) {
                const float oxf = (float)(ox - 2); // u_x = sx - qx
                float4 g = geo[d][qly + oy][qlx + ox];
                // corner lands on q iff floor(f)-q == 0 (weight 1-frac)
                //                  or floor(f)-q == -1 (weight frac)
                float tx = g.x + oxf;              // = floor(fx) - qx
                float ty = g.y + oyf;              // = floor(fy) - qy
                float wx = (tx == 0.0f) ? (1.0f - g.z) : ((tx == -1.0f) ? g.z : 0.0f);
                float wy = (ty == 0.0f) ? (1.0f - g.w) : ((ty == -1.0f) ? g.w : 0.0f);
                float wt = wx * wy;
                if (wt > 0.0f) {
                    float4 v = vw[d][qly + oy][qlx + ox];
                    acc[d][0] += wt * v.x;
                    acc[d][1] += wt * v.y;
                    acc[d][2] += wt * v.z;
                    acc[d][3] += wt * v.w;
                }
            }
        }
    }

    // ---- flush: each thread owns exactly one output pixel -> plain stores ----
    const size_t q = (size_t)(tY0 + qly) * Ww + (tX0 + qlx);
    bool flagged = true;
    if (flags)
        flagged = flags[(b * TILES_Y + tY) * TILES_X + tX] != 0;

#pragma unroll
    for (int d = 0; d < 2; ++d) {
        float* accImg = out + ((size_t)b * OUTC + (d ? 9 : 6)) * HW;
        float* accW   = out + ((size_t)b * OUTC + (d ? 17 : 16)) * HW;
        float s0 = acc[d][0];
        float s1 = acc[d][1];
        float s2 = acc[d][2];
        float sw = acc[d][3];
        if (flagged) {            // rare: merge prepass far contributions
            s0 += accImg[q];
            s1 += accImg[HW + q];
            s2 += accImg[2 * HW + q];
            sw += accW[q];
        }
        float inv = 1.0f / (sw + EPSF);
        accImg[q]          = s0 * inv;   // normalized f01i / f10i
        accImg[HW + q]     = s1 * inv;
        accImg[2 * HW + q] = s2 * inv;
        accW[q]            = sw;         // raw weight sum for erode
    }
}

// ---------------------------------------------------------------------------
// Full-2D erosion of raw weight sums: ch16/17 -> ch12/13.
// k==5 fast path: fully unrolled, coordinate-clamped (exact for min).
// ---------------------------------------------------------------------------
__global__ __launch_bounds__(256) void erode_kernel(float* __restrict__ out,
                                                    const int* __restrict__ kptr)
{
    int i = blockIdx.x * 256 + threadIdx.x;
    if (i >= Bb * HW) return;
    int b = i / HW;
    int p = i - b * HW;
    int y = p / Ww;
    int x = p - y * Ww;
    int k = *kptr;

    const float* s01 = out + ((size_t)b * OUTC + 16) * HW;
    const float* s10 = out + ((size_t)b * OUTC + 17) * HW;
    float* er01 = out + ((size_t)b * OUTC + 12) * HW;
    float* er10 = out + ((size_t)b * OUTC + 13) * HW;

    if (k <= 0) { er01[p] = s01[p]; er10[p] = s10[p]; return; }

    float m0 = INFINITY, m1 = INFINITY;
    if (k == 5) {
#pragma unroll
        for (int dy = -2; dy <= 2; ++dy) {
            int yy = min(max(y + dy, 0), Hh - 1);
#pragma unroll
            for (int dx = -2; dx <= 2; ++dx) {
                int xx = min(max(x + dx, 0), Ww - 1);
                int q = yy * Ww + xx;
                m0 = fminf(m0, s01[q]);
                m1 = fminf(m1, s10[q]);
            }
        }
    } else {
        int lo = (k - 1) / 2, hi = (k - 1) - lo;
        for (int dy = -lo; dy <= hi; ++dy) {
            int yy = y + dy;
            if (yy < 0 || yy >= Hh) continue;
            for (int dx = -lo; dx <= hi; ++dx) {
                int xx = x + dx;
                if (xx < 0 || xx >= Ww) continue;
                int q = yy * Ww + xx;
                m0 = fminf(m0, s01[q]);
                m1 = fminf(m1, s10[q]);
            }
        }
    }
    er01[p] = m0;
    er10[p] = m1;
}

// ---------------------------------------------------------------------------
// Fuse: dilate ch12/13 (k==5 fast path, clamped); mask = o/(o+eps); blend
// already-normalized ch6..11. Writes ch0..5, 16, 17.
// ---------------------------------------------------------------------------
__global__ __launch_bounds__(256) void fuse_kernel(float* __restrict__ out,
                                                   const int* __restrict__ kptr)
{
    int i = blockIdx.x * 256 + threadIdx.x;
    if (i >= Bb * HW) return;
    int b = i / HW;
    int p = i - b * HW;
    int y = p / Ww;
    int x = p - y * Ww;
    int k = *kptr;

    const float* er01 = out + ((size_t)b * OUTC + 12) * HW;
    const float* er10 = out + ((size_t)b * OUTC + 13) * HW;

    float o0, o1;
    if (k <= 0) {
        o0 = er01[p];
        o1 = er10[p];
    } else if (k == 5) {
        o0 = -INFINITY; o1 = -INFINITY;
#pragma unroll
        for (int dy = -2; dy <= 2; ++dy) {
            int yy = min(max(y + dy, 0), Hh - 1);
#pragma unroll
            for (int dx = -2; dx <= 2; ++dx) {
                int xx = min(max(x + dx, 0), Ww - 1);
                int q = yy * Ww + xx;
                o0 = fmaxf(o0, er01[q]);
                o1 = fmaxf(o1, er10[q]);
            }
        }
    } else {
        int lo = (k - 1) / 2, hi = (k - 1) - lo;
        o0 = -INFINITY; o1 = -INFINITY;
        for (int dy = -lo; dy <= hi; ++dy) {
            int yy = y + dy;
            if (yy < 0 || yy >= Hh) continue;
            for (int dx = -lo; dx <= hi; ++dx) {
                int xx = x + dx;
                if (xx < 0 || xx >= Ww) continue;
                int q = yy * Ww + xx;
                o0 = fmaxf(o0, er01[q]);
                o1 = fmaxf(o1, er10[q]);
            }
        }
    }

    float m01 = o0 / (o0 + EPSF);
    float m10 = o1 / (o1 + EPSF);

    float* ob = out + (size_t)b * OUTC * HW;
#pragma unroll
    for (int c = 0; c < 3; ++c) {
        float f01i = ob[((size_t)6 + c) * HW + p];   // already normalized by gather
        float f10i = ob[((size_t)9 + c) * HW + p];
        ob[((size_t)0 + c) * HW + p] = m01 * f01i + (1.0f - m01) * f10i;
        ob[((size_t)3 + c) * HW + p] = m10 * f10i + (1.0f - m10) * f01i;
    }
    ob[(size_t)16 * HW + p] = m01;
    ob[(size_t)17 * HW + p] = m10;
}

// ---------------------------------------------------------------------------
// Write 0.5*flow0 into ch12/13 (overwrites the parked erosions). Last.
// (ch14/15 = 0.5*flow1 already written by far_prepass_kernel.)
// ---------------------------------------------------------------------------
__global__ __launch_bounds__(256) void flow_kernel(const float* __restrict__ flow0,
                                                   float* __restrict__ out)
{
    int i = blockIdx.x * 256 + threadIdx.x;
    if (i >= Bb * 2 * HW) return;
    int b = i / (2 * HW);
    int r = i - b * 2 * HW;
    int c = r / HW;
    int p = r - c * HW;
    out[((size_t)b * OUTC + 12 + c) * HW + p] = 0.5f * flow0[((size_t)b * 2 + c) * HW + p];
}

extern "C" void kernel_launch(void* const* d_in, const int* in_sizes, int n_in,
                              void* d_out, int out_size, void* d_ws, size_t ws_size,
                              hipStream_t stream) {
    const float* img0  = (const float*)d_in[0];
    const float* img1  = (const float*)d_in[1];
    const float* flow0 = (const float*)d_in[2];
    const float* flow1 = (const float*)d_in[3];
    const float* z0    = (const float*)d_in[4];
    const float* z1    = (const float*)d_in[5];
    const int*   kptr  = (const int*)d_in[6];
    float* out = (float*)d_out;

    // zero the 8 accumulator planes (ch6..11 contiguous, ch16..17 contiguous)
    for (int b = 0; b < Bb; ++b) {
        hipMemsetAsync(out + ((size_t)b * OUTC + 6) * HW, 0, (size_t)6 * HW * sizeof(float), stream);
        hipMemsetAsync(out + ((size_t)b * OUTC + 16) * HW, 0, (size_t)2 * HW * sizeof(float), stream);
    }

    int* flags = nullptr;
    if (d_ws && ws_size >= (size_t)NTILES * sizeof(int)) {
        flags = (int*)d_ws;
        hipMemsetAsync(flags, 0, (size_t)NTILES * sizeof(int), stream);
    }

    int n = Bb * HW;
    int blocks = (n + 255) / 256;

    far_prepass_kernel<<<blocks, 256, 0, stream>>>(img0, img1, flow0, flow1, z0, z1, out, flags);
    gather_splat_kernel<<<NTILES, 256, 0, stream>>>(img0, img1, flow0, flow1, z0, z1, out, flags);
    erode_kernel<<<blocks, 256, 0, stream>>>(out, kptr);
    fuse_kernel<<<blocks, 256, 0, stream>>>(out, kptr);
    int n2 = Bb * 2 * HW;
    flow_kernel<<<(n2 + 255) / 256, 256, 0, stream>>>(flow0, out);
}

// Round 5
// 302.498 us; speedup vs baseline: 1.9513x; 1.0441x over previous
//
#include <hip/hip_runtime.h>
#include <math.h>

#define Hh 720
#define Ww 1280
#define Bb 2
#define HW (Hh*Ww)
#define OUTC 18
#define EPSF 1e-7f

// R5 = R4 (passing gather softsplat, reference-exact weights) +
//  (a) two-phase LDS staging in the gather (per-direction) -> LDS 31->15.4 KB,
//      occupancy 5->8 blocks/CU;
//  (b) LDS-tiled SEPARABLE morphology: erode5 (row-min+col-min) and
//      fuse5 (row-max+col-max + blend) for k<=5, replacing the 50-scattered-
//      global-loads-per-thread erode/fuse. Legacy kernels retained as k>5
//      fallbacks (k lives on device; host cannot branch on it).
#define DMAX 2.0f
#define OWN_W 32
#define OWN_H 8
#define SRC_W (OWN_W + 5)        // 37
#define SRC_H (OWN_H + 5)        // 13
#define NSRC (SRC_W * SRC_H)     // 481
#define TILES_X (Ww / OWN_W)     // 40
#define TILES_Y (Hh / OWN_H)     // 90
#define NTILES (Bb * TILES_X * TILES_Y)   // 7200 (divisible by 8)

// morphology tile max extents (k<=5: halo k-1<=4 per pass)
#define EW (OWN_W + 4)           // 36
#define EH (OWN_H + 4)           // 12

// ---------------------------------------------------------------------------
// Rare-path: sources with |0.5*flow| > DMAX splat directly to global with
// atomics (acc planes pre-zeroed) and flag the target tiles. Runs first.
// Also writes ch14/15 = 0.5*flow1. Reference fx = x + dx arithmetic.
// ---------------------------------------------------------------------------
__global__ __launch_bounds__(256) void far_prepass_kernel(
    const float* __restrict__ img0, const float* __restrict__ img1,
    const float* __restrict__ flow0, const float* __restrict__ flow1,
    const float* __restrict__ z0, const float* __restrict__ z1,
    float* __restrict__ out, int* __restrict__ flags)
{
    int i = blockIdx.x * 256 + threadIdx.x;
    if (i >= Bb * HW) return;
    int b = i / HW;
    int p = i - b * HW;
    int y = p / Ww;
    int x = p - y * Ww;

    float f1x = flow1[((size_t)b * 2 + 1) * HW + p];
    float f1y = flow1[((size_t)b * 2 + 0) * HW + p];
    float f0x = flow0[((size_t)b * 2 + 1) * HW + p];
    float f0y = flow0[((size_t)b * 2 + 0) * HW + p];
    float dxs[2] = { 0.5f * f1x, 0.5f * f0x };   // d=0: flow1, d=1: flow0
    float dys[2] = { 0.5f * f1y, 0.5f * f0y };

    // ch14 = 0.5*flow1[ch0], ch15 = 0.5*flow1[ch1]
    out[((size_t)b * OUTC + 14) * HW + p] = 0.5f * f1y;
    out[((size_t)b * OUTC + 15) * HW + p] = 0.5f * f1x;

    for (int d = 0; d < 2; ++d) {
        float dx = dxs[d], dy = dys[d];
        if (fabsf(dx) <= DMAX && fabsf(dy) <= DMAX) continue; // local: gather handles

        const float* img = d ? img1 : img0;
        const float* met = d ? z0 : z1;
        float fx = (float)x + dx;
        float fy = (float)y + dy;
        float w  = expf(met[(size_t)b * HW + p]);
        float v0 = img[((size_t)b * 3 + 0) * HW + p] * w;
        float v1 = img[((size_t)b * 3 + 1) * HW + p] * w;
        float v2 = img[((size_t)b * 3 + 2) * HW + p] * w;

        float x0f = floorf(fx), y0f = floorf(fy);
        float x1f = x0f + 1.0f, y1f = y0f + 1.0f;
        int   x0  = (int)x0f,  y0i = (int)y0f;
        float wxs[2] = { x1f - fx, fx - x0f };
        float wys[2] = { y1f - fy, fy - y0f };

        float* accImg = out + ((size_t)b * OUTC + (d ? 9 : 6)) * HW;
        float* accW   = out + ((size_t)b * OUTC + (d ? 17 : 16)) * HW;

        for (int cy = 0; cy < 2; ++cy) {
            int yy = y0i + cy;
            if (yy < 0 || yy >= Hh) continue;
            for (int cx = 0; cx < 2; ++cx) {
                int xx = x0 + cx;
                if (xx < 0 || xx >= Ww) continue;
                float wt = wxs[cx] * wys[cy];
                if (wt == 0.0f) continue;
                int q = yy * Ww + xx;
                atomicAdd(accImg + q,          v0 * wt);
                atomicAdd(accImg + HW + q,     v1 * wt);
                atomicAdd(accImg + 2 * HW + q, v2 * wt);
                atomicAdd(accW + q,            w  * wt);
                if (flags)
                    flags[(b * TILES_Y + yy / OWN_H) * TILES_X + xx / OWN_W] = 1;
            }
        }
    }
}

// ---------------------------------------------------------------------------
// Gather splat (R4 weight arithmetic, bit-exact vs reference scatter).
// R5: per-direction two-phase LDS staging (halved LDS -> higher occupancy).
// ---------------------------------------------------------------------------
__global__ __launch_bounds__(256) void gather_splat_kernel(
    const float* __restrict__ img0, const float* __restrict__ img1,
    const float* __restrict__ flow0, const float* __restrict__ flow1,
    const float* __restrict__ z0, const float* __restrict__ z1,
    float* __restrict__ out, const int* __restrict__ flags)
{
    __shared__ float4 geo[SRC_H][SRC_W];  // {offx, offy, fracx, fracy}; off=1e9 if dead
    __shared__ float4 vw [SRC_H][SRC_W];  // {v0*w, v1*w, v2*w, w}

    // XCD-aware bijective swizzle (NTILES % 8 == 0): contiguous tile runs per XCD.
    int wg   = blockIdx.x;
    int wgid = (wg & 7) * (NTILES / 8) + (wg >> 3);
    int b    = wgid / (TILES_X * TILES_Y);
    int rr   = wgid - b * (TILES_X * TILES_Y);
    int tY   = rr / TILES_X;
    int tX   = rr - tY * TILES_X;
    const int tX0 = tX * OWN_W;
    const int tY0 = tY * OWN_H;

    const int qlx = threadIdx.x & (OWN_W - 1);
    const int qly = threadIdx.x >> 5;

    float acc[2][4];
#pragma unroll
    for (int d = 0; d < 2; ++d)
#pragma unroll
        for (int c = 0; c < 4; ++c) acc[d][c] = 0.0f;

#pragma unroll
    for (int d = 0; d < 2; ++d) {
        if (d) __syncthreads();   // WAR: finish prior gather before restaging

        const float* flw = d ? flow0 : flow1;   // dir0: img0 by 0.5*flow1 (w=exp z1)
        const float* met = d ? z0 : z1;         // dir1: img1 by 0.5*flow0 (w=exp z0)
        const float* img = d ? img1 : img0;

        for (int c = threadIdx.x; c < NSRC; c += 256) {
            int cy = c / SRC_W, cx = c - cy * SRC_W;
            int sx = tX0 + cx - 2;
            int sy = tY0 + cy - 2;
            bool inimg = (sx >= 0) && (sx < Ww) && (sy >= 0) && (sy < Hh);
            int p = min(max(sy, 0), Hh - 1) * Ww + min(max(sx, 0), Ww - 1);

            float fxv = flw[((size_t)b * 2 + 1) * HW + p];
            float fyv = flw[((size_t)b * 2 + 0) * HW + p];
            float zz  = met[(size_t)b * HW + p];
            float i0  = img[((size_t)b * 3 + 0) * HW + p];
            float i1  = img[((size_t)b * 3 + 1) * HW + p];
            float i2  = img[((size_t)b * 3 + 2) * HW + p];

            float dx = 0.5f * fxv, dy = 0.5f * fyv;
            bool l = inimg && (fabsf(dx) <= DMAX) && (fabsf(dy) <= DMAX);
            float w = l ? expf(zz) : 0.0f;

            // reference-rounded decomposition (bit-exact weights):
            float fx = (float)sx + dx, fy = (float)sy + dy;
            float x0f = floorf(fx), y0f = floorf(fy);
            geo[cy][cx] = make_float4(l ? x0f - (float)sx : 1e9f,
                                      l ? y0f - (float)sy : 1e9f,
                                      fx - x0f, fy - y0f);
            vw[cy][cx] = make_float4(i0 * w, i1 * w, i2 * w, w);
        }
        __syncthreads();

        // gather: register accumulation over the 6x6 candidate offsets
#pragma unroll
        for (int oy = 0; oy < 6; ++oy) {
            const float oyf = (float)(oy - 2);     // u_y = sy - qy
#pragma unroll
            for (int ox = 0; ox < 6; ++ox) {
                const float oxf = (float)(ox - 2); // u_x = sx - qx
                float4 g = geo[qly + oy][qlx + ox];
                // corner lands on q iff floor(f)-q == 0 (weight 1-frac)
                //                  or floor(f)-q == -1 (weight frac)
                float tx = g.x + oxf;              // = floor(fx) - qx
                float ty = g.y + oyf;              // = floor(fy) - qy
                float wx = (tx == 0.0f) ? (1.0f - g.z) : ((tx == -1.0f) ? g.z : 0.0f);
                float wy = (ty == 0.0f) ? (1.0f - g.w) : ((ty == -1.0f) ? g.w : 0.0f);
                float wt = wx * wy;
                if (wt > 0.0f) {
                    float4 v = vw[qly + oy][qlx + ox];
                    acc[d][0] += wt * v.x;
                    acc[d][1] += wt * v.y;
                    acc[d][2] += wt * v.z;
                    acc[d][3] += wt * v.w;
                }
            }
        }
    }

    // ---- flush: each thread owns exactly one output pixel -> plain stores ----
    const size_t q = (size_t)(tY0 + qly) * Ww + (tX0 + qlx);
    bool flagged = true;
    if (flags)
        flagged = flags[(b * TILES_Y + tY) * TILES_X + tX] != 0;

#pragma unroll
    for (int d = 0; d < 2; ++d) {
        float* accImg = out + ((size_t)b * OUTC + (d ? 9 : 6)) * HW;
        float* accW   = out + ((size_t)b * OUTC + (d ? 17 : 16)) * HW;
        float s0 = acc[d][0];
        float s1 = acc[d][1];
        float s2 = acc[d][2];
        float sw = acc[d][3];
        if (flagged) {            // rare: merge prepass far contributions
            s0 += accImg[q];
            s1 += accImg[HW + q];
            s2 += accImg[2 * HW + q];
            sw += accW[q];
        }
        float inv = 1.0f / (sw + EPSF);
        accImg[q]          = s0 * inv;   // normalized f01i / f10i
        accImg[HW + q]     = s1 * inv;
        accImg[2 * HW + q] = s2 * inv;
        accW[q]            = sw;         // raw weight sum for erode
    }
}

// ---------------------------------------------------------------------------
// LDS-tiled separable erosion (k <= 5): ch16/17 -> ch12/13.
// Clamped staging is exact for min (clamped duplicates are valid in-window
// pixels under SAME padding with +inf identity). k<=0: plain copy.
// ---------------------------------------------------------------------------
__global__ __launch_bounds__(256) void erode5_kernel(float* __restrict__ out,
                                                     const int* __restrict__ kptr)
{
    __shared__ float s2  [2][EH][EW];
    __shared__ float rmin[2][EH][OWN_W];

    int k = *kptr;
    if (k > 5) return;          // legacy erode_kernel handles

    int wg   = blockIdx.x;
    int wgid = (wg & 7) * (NTILES / 8) + (wg >> 3);
    int b    = wgid / (TILES_X * TILES_Y);
    int rr   = wgid - b * (TILES_X * TILES_Y);
    int tY   = rr / TILES_X;
    int tX   = rr - tY * TILES_X;
    const int tX0 = tX * OWN_W;
    const int tY0 = tY * OWN_H;

    const float* s01 = out + ((size_t)b * OUTC + 16) * HW;
    const float* s10 = out + ((size_t)b * OUTC + 17) * HW;
    float* er01 = out + ((size_t)b * OUTC + 12) * HW;
    float* er10 = out + ((size_t)b * OUTC + 13) * HW;

    const int r  = threadIdx.x >> 5;
    const int xc = threadIdx.x & 31;
    const size_t qp = (size_t)(tY0 + r) * Ww + (tX0 + xc);

    if (k <= 0) { er01[qp] = s01[qp]; er10[qp] = s10[qp]; return; }

    const int lo = (k - 1) / 2;
    const int ew = OWN_W + k - 1;    // <= 36
    const int eh = OWN_H + k - 1;    // <= 12

    for (int c = threadIdx.x; c < eh * ew; c += 256) {
        int i = c / ew, j = c - i * ew;
        int gy = min(max(tY0 - lo + i, 0), Hh - 1);
        int gx = min(max(tX0 - lo + j, 0), Ww - 1);
        size_t p = (size_t)gy * Ww + gx;
        s2[0][i][j] = s01[p];
        s2[1][i][j] = s10[p];
    }
    __syncthreads();

    for (int c = threadIdx.x; c < eh * OWN_W; c += 256) {
        int i = c / OWN_W, x = c - i * OWN_W;
        float m0 = s2[0][i][x], m1 = s2[1][i][x];
        for (int t = 1; t < k; ++t) {
            m0 = fminf(m0, s2[0][i][x + t]);
            m1 = fminf(m1, s2[1][i][x + t]);
        }
        rmin[0][i][x] = m0;
        rmin[1][i][x] = m1;
    }
    __syncthreads();

    float m0 = rmin[0][r][xc], m1 = rmin[1][r][xc];
    for (int t = 1; t < k; ++t) {
        m0 = fminf(m0, rmin[0][r + t][xc]);
        m1 = fminf(m1, rmin[1][r + t][xc]);
    }
    er01[qp] = m0;
    er10[qp] = m1;
}

// ---------------------------------------------------------------------------
// LDS-tiled separable dilation of ch12/13 (k <= 5) + mask + blend.
// Writes ch0..5, 16, 17. k<=0: open = er pointwise.
// ---------------------------------------------------------------------------
__global__ __launch_bounds__(256) void fuse5_kernel(float* __restrict__ out,
                                                    const int* __restrict__ kptr)
{
    __shared__ float e2  [2][EH][EW];
    __shared__ float rmax[2][EH][OWN_W];

    int k = *kptr;
    if (k > 5) return;          // legacy fuse_kernel handles

    int wg   = blockIdx.x;
    int wgid = (wg & 7) * (NTILES / 8) + (wg >> 3);
    int b    = wgid / (TILES_X * TILES_Y);
    int rr   = wgid - b * (TILES_X * TILES_Y);
    int tY   = rr / TILES_X;
    int tX   = rr - tY * TILES_X;
    const int tX0 = tX * OWN_W;
    const int tY0 = tY * OWN_H;

    const float* er01 = out + ((size_t)b * OUTC + 12) * HW;
    const float* er10 = out + ((size_t)b * OUTC + 13) * HW;

    const int r  = threadIdx.x >> 5;
    const int xc = threadIdx.x & 31;
    const size_t qp = (size_t)(tY0 + r) * Ww + (tX0 + xc);

    float o0, o1;
    if (k <= 0) {
        o0 = er01[qp];
        o1 = er10[qp];
    } else {
        const int lo = (k - 1) / 2;
        const int ew = OWN_W + k - 1;
        const int eh = OWN_H + k - 1;

        for (int c = threadIdx.x; c < eh * ew; c += 256) {
            int i = c / ew, j = c - i * ew;
            int gy = min(max(tY0 - lo + i, 0), Hh - 1);
            int gx = min(max(tX0 - lo + j, 0), Ww - 1);
            size_t p = (size_t)gy * Ww + gx;
            e2[0][i][j] = er01[p];
            e2[1][i][j] = er10[p];
        }
        __syncthreads();

        for (int c = threadIdx.x; c < eh * OWN_W; c += 256) {
            int i = c / OWN_W, x = c - i * OWN_W;
            float m0 = e2[0][i][x], m1 = e2[1][i][x];
            for (int t = 1; t < k; ++t) {
                m0 = fmaxf(m0, e2[0][i][x + t]);
                m1 = fmaxf(m1, e2[1][i][x + t]);
            }
            rmax[0][i][x] = m0;
            rmax[1][i][x] = m1;
        }
        __syncthreads();

        o0 = rmax[0][r][xc]; o1 = rmax[1][r][xc];
        for (int t = 1; t < k; ++t) {
            o0 = fmaxf(o0, rmax[0][r + t][xc]);
            o1 = fmaxf(o1, rmax[1][r + t][xc]);
        }
    }

    float m01 = o0 / (o0 + EPSF);
    float m10 = o1 / (o1 + EPSF);

    float* ob = out + (size_t)b * OUTC * HW;
#pragma unroll
    for (int c = 0; c < 3; ++c) {
        float f01i = ob[((size_t)6 + c) * HW + qp];   // already normalized by gather
        float f10i = ob[((size_t)9 + c) * HW + qp];
        ob[((size_t)0 + c) * HW + qp] = m01 * f01i + (1.0f - m01) * f10i;
        ob[((size_t)3 + c) * HW + qp] = m10 * f10i + (1.0f - m10) * f01i;
    }
    ob[(size_t)16 * HW + qp] = m01;
    ob[(size_t)17 * HW + qp] = m10;
}

// ---------------------------------------------------------------------------
// Legacy full-2D erosion: k > 5 fallback only.
// ---------------------------------------------------------------------------
__global__ __launch_bounds__(256) void erode_kernel(float* __restrict__ out,
                                                    const int* __restrict__ kptr)
{
    int k = *kptr;
    if (k <= 5) return;         // erode5_kernel handled
    int i = blockIdx.x * 256 + threadIdx.x;
    if (i >= Bb * HW) return;
    int b = i / HW;
    int p = i - b * HW;
    int y = p / Ww;
    int x = p - y * Ww;

    const float* s01 = out + ((size_t)b * OUTC + 16) * HW;
    const float* s10 = out + ((size_t)b * OUTC + 17) * HW;
    float* er01 = out + ((size_t)b * OUTC + 12) * HW;
    float* er10 = out + ((size_t)b * OUTC + 13) * HW;

    int lo = (k - 1) / 2, hi = (k - 1) - lo;
    float m0 = INFINITY, m1 = INFINITY;
    for (int dy = -lo; dy <= hi; ++dy) {
        int yy = y + dy;
        if (yy < 0 || yy >= Hh) continue;
        for (int dx = -lo; dx <= hi; ++dx) {
            int xx = x + dx;
            if (xx < 0 || xx >= Ww) continue;
            int q = yy * Ww + xx;
            m0 = fminf(m0, s01[q]);
            m1 = fminf(m1, s10[q]);
        }
    }
    er01[p] = m0;
    er10[p] = m1;
}

// ---------------------------------------------------------------------------
// Legacy fuse: k > 5 fallback only.
// ---------------------------------------------------------------------------
__global__ __launch_bounds__(256) void fuse_kernel(float* __restrict__ out,
                                                   const int* __restrict__ kptr)
{
    int k = *kptr;
    if (k <= 5) return;         // fuse5_kernel handled
    int i = blockIdx.x * 256 + threadIdx.x;
    if (i >= Bb * HW) return;
    int b = i / HW;
    int p = i - b * HW;
    int y = p / Ww;
    int x = p - y * Ww;

    const float* er01 = out + ((size_t)b * OUTC + 12) * HW;
    const float* er10 = out + ((size_t)b * OUTC + 13) * HW;

    int lo = (k - 1) / 2, hi = (k - 1) - lo;
    float o0 = -INFINITY, o1 = -INFINITY;
    for (int dy = -lo; dy <= hi; ++dy) {
        int yy = y + dy;
        if (yy < 0 || yy >= Hh) continue;
        for (int dx = -lo; dx <= hi; ++dx) {
            int xx = x + dx;
            if (xx < 0 || xx >= Ww) continue;
            int q = yy * Ww + xx;
            o0 = fmaxf(o0, er01[q]);
            o1 = fmaxf(o1, er10[q]);
        }
    }

    float m01 = o0 / (o0 + EPSF);
    float m10 = o1 / (o1 + EPSF);

    float* ob = out + (size_t)b * OUTC * HW;
#pragma unroll
    for (int c = 0; c < 3; ++c) {
        float f01i = ob[((size_t)6 + c) * HW + p];
        float f10i = ob[((size_t)9 + c) * HW + p];
        ob[((size_t)0 + c) * HW + p] = m01 * f01i + (1.0f - m01) * f10i;
        ob[((size_t)3 + c) * HW + p] = m10 * f10i + (1.0f - m10) * f01i;
    }
    ob[(size_t)16 * HW + p] = m01;
    ob[(size_t)17 * HW + p] = m10;
}

// ---------------------------------------------------------------------------
// Write 0.5*flow0 into ch12/13 (overwrites the parked erosions). Last.
// (ch14/15 = 0.5*flow1 already written by far_prepass_kernel.)
// ---------------------------------------------------------------------------
__global__ __launch_bounds__(256) void flow_kernel(const float* __restrict__ flow0,
                                                   float* __restrict__ out)
{
    int i = blockIdx.x * 256 + threadIdx.x;
    if (i >= Bb * 2 * HW) return;
    int b = i / (2 * HW);
    int r = i - b * 2 * HW;
    int c = r / HW;
    int p = r - c * HW;
    out[((size_t)b * OUTC + 12 + c) * HW + p] = 0.5f * flow0[((size_t)b * 2 + c) * HW + p];
}

extern "C" void kernel_launch(void* const* d_in, const int* in_sizes, int n_in,
                              void* d_out, int out_size, void* d_ws, size_t ws_size,
                              hipStream_t stream) {
    const float* img0  = (const float*)d_in[0];
    const float* img1  = (const float*)d_in[1];
    const float* flow0 = (const float*)d_in[2];
    const float* flow1 = (const float*)d_in[3];
    const float* z0    = (const float*)d_in[4];
    const float* z1    = (const float*)d_in[5];
    const int*   kptr  = (const int*)d_in[6];
    float* out = (float*)d_out;

    // zero the 8 accumulator planes (ch6..11 contiguous, ch16..17 contiguous)
    for (int b = 0; b < Bb; ++b) {
        hipMemsetAsync(out + ((size_t)b * OUTC + 6) * HW, 0, (size_t)6 * HW * sizeof(float), stream);
        hipMemsetAsync(out + ((size_t)b * OUTC + 16) * HW, 0, (size_t)2 * HW * sizeof(float), stream);
    }

    int* flags = nullptr;
    if (d_ws && ws_size >= (size_t)NTILES * sizeof(int)) {
        flags = (int*)d_ws;
        hipMemsetAsync(flags, 0, (size_t)NTILES * sizeof(int), stream);
    }

    int n = Bb * HW;
    int blocks = (n + 255) / 256;

    far_prepass_kernel<<<blocks, 256, 0, stream>>>(img0, img1, flow0, flow1, z0, z1, out, flags);
    gather_splat_kernel<<<NTILES, 256, 0, stream>>>(img0, img1, flow0, flow1, z0, z1, out, flags);
    erode5_kernel<<<NTILES, 256, 0, stream>>>(out, kptr);
    erode_kernel<<<blocks, 256, 0, stream>>>(out, kptr);   // k>5 fallback (no-op else)
    fuse5_kernel<<<NTILES, 256, 0, stream>>>(out, kptr);
    fuse_kernel<<<blocks, 256, 0, stream>>>(out, kptr);    // k>5 fallback (no-op else)
    int n2 = Bb * 2 * HW;
    flow_kernel<<<(n2 + 255) / 256, 256, 0, stream>>>(flow0, out);
}

// Round 7
// 294.560 us; speedup vs baseline: 2.0039x; 1.0270x over previous
//
#include <hip/hip_runtime.h>
#include <math.h>

#define Hh 720
#define Ww 1280
#define Bb 2
#define HW (Hh*Ww)
#define OUTC 18
#define EPSF 1e-7f

// R7 == R6 (infra failure last round, no kernel defect found on review).
// R6 = R4 gather (single-phase staging, 85us proven; R5's two-phase staging
// serialized the critical path and regressed to 95us) + R5 separable
// morphology + LAUNCH-COUNT COLLAPSE (12 enqueued ops -> 5):
//   zero_kernel (replaces 5 memsets, also zeroes flags)
//   far_prepass (also writes ALL four scaled-flow planes ch12..15)
//   gather_splat
//   erode5 (k>5 legacy merged in; erosion parked in d_ws)
//   fuse5  (k>5 legacy merged in; reads erosion from d_ws)
// Fallback if ws too small: erosion in ch12/13 + trailing flow_kernel.
#define DMAX 2.0f
#define OWN_W 32
#define OWN_H 8
#define SRC_W (OWN_W + 5)        // 37
#define SRC_H (OWN_H + 5)        // 13
#define NSRC (SRC_W * SRC_H)     // 481
#define TILES_X (Ww / OWN_W)     // 40
#define TILES_Y (Hh / OWN_H)     // 90
#define NTILES (Bb * TILES_X * TILES_Y)   // 7200 (divisible by 8; == Bb*HW/256)

// morphology tile max extents (k<=5: halo k-1<=4 per pass)
#define EW (OWN_W + 4)           // 36
#define EH (OWN_H + 4)           // 12

// ---------------------------------------------------------------------------
// Zero the 8 accumulator planes per batch (ch6..11, ch16/17) + flags.
// One launch replacing 5 hipMemsetAsync dispatches.
// ---------------------------------------------------------------------------
__global__ __launch_bounds__(256) void zero_kernel(float* __restrict__ out,
                                                   int* __restrict__ flags)
{
    size_t idx = (size_t)blockIdx.x * 256 + threadIdx.x;
    if (flags) {
        for (size_t f = idx; f < NTILES; f += (size_t)gridDim.x * 256)
            flags[f] = 0;
    }
    const size_t n4 = (size_t)Bb * 8 * HW / 4;   // float4 count
    for (size_t i = idx; i < n4; i += (size_t)gridDim.x * 256) {
        size_t e = i * 4;
        int b = (int)(e / ((size_t)8 * HW));
        size_t r = e - (size_t)b * 8 * HW;
        int c = (int)(r / HW);                   // 0..7
        size_t p = r - (size_t)c * HW;
        int ch = (c < 6) ? (6 + c) : (16 + (c - 6));
        *(float4*)(out + ((size_t)b * OUTC + ch) * HW + p) = make_float4(0.f, 0.f, 0.f, 0.f);
    }
}

// ---------------------------------------------------------------------------
// Rare-path: sources with |0.5*flow| > DMAX splat directly to global with
// atomics (acc planes pre-zeroed) and flag the target tiles. Runs after zero.
// Also writes ch14/15 = 0.5*flow1, and (ws mode) ch12/13 = 0.5*flow0.
// ---------------------------------------------------------------------------
__global__ __launch_bounds__(256) void far_prepass_kernel(
    const float* __restrict__ img0, const float* __restrict__ img1,
    const float* __restrict__ flow0, const float* __restrict__ flow1,
    const float* __restrict__ z0, const float* __restrict__ z1,
    float* __restrict__ out, int* __restrict__ flags, int wf01)
{
    int i = blockIdx.x * 256 + threadIdx.x;
    if (i >= Bb * HW) return;
    int b = i / HW;
    int p = i - b * HW;
    int y = p / Ww;
    int x = p - y * Ww;

    float f1x = flow1[((size_t)b * 2 + 1) * HW + p];
    float f1y = flow1[((size_t)b * 2 + 0) * HW + p];
    float f0x = flow0[((size_t)b * 2 + 1) * HW + p];
    float f0y = flow0[((size_t)b * 2 + 0) * HW + p];
    float dxs[2] = { 0.5f * f1x, 0.5f * f0x };   // d=0: flow1, d=1: flow0
    float dys[2] = { 0.5f * f1y, 0.5f * f0y };

    // ch14 = 0.5*flow1[ch0], ch15 = 0.5*flow1[ch1]
    out[((size_t)b * OUTC + 14) * HW + p] = 0.5f * f1y;
    out[((size_t)b * OUTC + 15) * HW + p] = 0.5f * f1x;
    if (wf01) {   // ws mode: ch12/13 are free for flows now
        out[((size_t)b * OUTC + 12) * HW + p] = 0.5f * f0y;
        out[((size_t)b * OUTC + 13) * HW + p] = 0.5f * f0x;
    }

    for (int d = 0; d < 2; ++d) {
        float dx = dxs[d], dy = dys[d];
        if (fabsf(dx) <= DMAX && fabsf(dy) <= DMAX) continue; // local: gather handles

        const float* img = d ? img1 : img0;
        const float* met = d ? z0 : z1;
        float fx = (float)x + dx;
        float fy = (float)y + dy;
        float w  = expf(met[(size_t)b * HW + p]);
        float v0 = img[((size_t)b * 3 + 0) * HW + p] * w;
        float v1 = img[((size_t)b * 3 + 1) * HW + p] * w;
        float v2 = img[((size_t)b * 3 + 2) * HW + p] * w;

        float x0f = floorf(fx), y0f = floorf(fy);
        float x1f = x0f + 1.0f, y1f = y0f + 1.0f;
        int   x0  = (int)x0f,  y0i = (int)y0f;
        float wxs[2] = { x1f - fx, fx - x0f };
        float wys[2] = { y1f - fy, fy - y0f };

        float* accImg = out + ((size_t)b * OUTC + (d ? 9 : 6)) * HW;
        float* accW   = out + ((size_t)b * OUTC + (d ? 17 : 16)) * HW;

        for (int cy = 0; cy < 2; ++cy) {
            int yy = y0i + cy;
            if (yy < 0 || yy >= Hh) continue;
            for (int cx = 0; cx < 2; ++cx) {
                int xx = x0 + cx;
                if (xx < 0 || xx >= Ww) continue;
                float wt = wxs[cx] * wys[cy];
                if (wt == 0.0f) continue;
                int q = yy * Ww + xx;
                atomicAdd(accImg + q,          v0 * wt);
                atomicAdd(accImg + HW + q,     v1 * wt);
                atomicAdd(accImg + 2 * HW + q, v2 * wt);
                atomicAdd(accW + q,            w  * wt);
                if (flags)
                    flags[(b * TILES_Y + yy / OWN_H) * TILES_X + xx / OWN_W] = 1;
            }
        }
    }
}

// ---------------------------------------------------------------------------
// Gather splat — R4 structure exactly (single-phase staging of BOTH dirs,
// 31KB LDS, max in-flight loads; proven 85us @ 70% VALUBusy).
// ---------------------------------------------------------------------------
__global__ __launch_bounds__(256) void gather_splat_kernel(
    const float* __restrict__ img0, const float* __restrict__ img1,
    const float* __restrict__ flow0, const float* __restrict__ flow1,
    const float* __restrict__ z0, const float* __restrict__ z1,
    float* __restrict__ out, const int* __restrict__ flags)
{
    __shared__ float4 geo[2][SRC_H][SRC_W];  // {offx, offy, fracx, fracy}; off=1e9 if dead
    __shared__ float4 vw [2][SRC_H][SRC_W];  // {v0*w, v1*w, v2*w, w}

    // XCD-aware bijective swizzle (NTILES % 8 == 0): contiguous tile runs per XCD.
    int wg   = blockIdx.x;
    int wgid = (wg & 7) * (NTILES / 8) + (wg >> 3);
    int b    = wgid / (TILES_X * TILES_Y);
    int rr   = wgid - b * (TILES_X * TILES_Y);
    int tY   = rr / TILES_X;
    int tX   = rr - tY * TILES_X;
    const int tX0 = tX * OWN_W;
    const int tY0 = tY * OWN_H;

    // ---- stage the source window (plain LDS writes, every cell written) ----
    for (int c = threadIdx.x; c < NSRC; c += 256) {
        int cy = c / SRC_W, cx = c - cy * SRC_W;
        int sx = tX0 + cx - 2;
        int sy = tY0 + cy - 2;
        bool inimg = (sx >= 0) && (sx < Ww) && (sy >= 0) && (sy < Hh);
        int p = min(max(sy, 0), Hh - 1) * Ww + min(max(sx, 0), Ww - 1);

        float f1x = flow1[((size_t)b * 2 + 1) * HW + p];
        float f1y = flow1[((size_t)b * 2 + 0) * HW + p];
        float f0x = flow0[((size_t)b * 2 + 1) * HW + p];
        float f0y = flow0[((size_t)b * 2 + 0) * HW + p];
        float zz1 = z1[(size_t)b * HW + p];
        float zz0 = z0[(size_t)b * HW + p];
        float a0 = img0[((size_t)b * 3 + 0) * HW + p];
        float a1 = img0[((size_t)b * 3 + 1) * HW + p];
        float a2 = img0[((size_t)b * 3 + 2) * HW + p];
        float c0 = img1[((size_t)b * 3 + 0) * HW + p];
        float c1 = img1[((size_t)b * 3 + 1) * HW + p];
        float c2 = img1[((size_t)b * 3 + 2) * HW + p];

        float dx0 = 0.5f * f1x, dy0 = 0.5f * f1y;   // dir0: img0 by 0.5*flow1
        float dx1 = 0.5f * f0x, dy1 = 0.5f * f0y;   // dir1: img1 by 0.5*flow0
        bool l0 = inimg && (fabsf(dx0) <= DMAX) && (fabsf(dy0) <= DMAX);
        bool l1 = inimg && (fabsf(dx1) <= DMAX) && (fabsf(dy1) <= DMAX);
        float w0 = l0 ? expf(zz1) : 0.0f;
        float w1 = l1 ? expf(zz0) : 0.0f;

        // reference-rounded decomposition (bit-exact weights):
        //   fx = (float)sx + dx  (same rounding as gx + flow*0.5 in the ref)
        //   frac = fx - floor(fx)  and  1-frac == floor(fx)+1-fx  (both exact)
        float fx0 = (float)sx + dx0, fy0 = (float)sy + dy0;
        float fx1 = (float)sx + dx1, fy1 = (float)sy + dy1;
        float x0f0 = floorf(fx0), y0f0 = floorf(fy0);
        float x0f1 = floorf(fx1), y0f1 = floorf(fy1);

        geo[0][cy][cx] = make_float4(l0 ? x0f0 - (float)sx : 1e9f,
                                     l0 ? y0f0 - (float)sy : 1e9f,
                                     fx0 - x0f0, fy0 - y0f0);
        geo[1][cy][cx] = make_float4(l1 ? x0f1 - (float)sx : 1e9f,
                                     l1 ? y0f1 - (float)sy : 1e9f,
                                     fx1 - x0f1, fy1 - y0f1);
        vw[0][cy][cx] = make_float4(a0 * w0, a1 * w0, a2 * w0, w0);
        vw[1][cy][cx] = make_float4(c0 * w1, c1 * w1, c2 * w1, w1);
    }
    __syncthreads();

    // ---- gather: register accumulation over the 6x6 candidate offsets ----
    const int qlx = threadIdx.x & (OWN_W - 1);
    const int qly = threadIdx.x >> 5;

    float acc[2][4];
#pragma unroll
    for (int d = 0; d < 2; ++d)
#pragma unroll
        for (int c = 0; c < 4; ++c) acc[d][c] = 0.0f;

#pragma unroll
    for (int d = 0; d < 2; ++d) {
#pragma unroll
        for (int oy = 0; oy < 6; ++oy) {
            const float oyf = (float)(oy - 2);     // u_y = sy - qy
#pragma unroll
            for (int ox = 0; ox < 6; ++ox) {
                const float oxf = (float)(ox - 2); // u_x = sx - qx
                float4 g = geo[d][qly + oy][qlx + ox];
                // corner lands on q iff floor(f)-q == 0 (weight 1-frac)
                //                  or floor(f)-q == -1 (weight frac)
                float tx = g.x + oxf;              // = floor(fx) - qx
                float ty = g.y + oyf;              // = floor(fy) - qy
                float wx = (tx == 0.0f) ? (1.0f - g.z) : ((tx == -1.0f) ? g.z : 0.0f);
                float wy = (ty == 0.0f) ? (1.0f - g.w) : ((ty == -1.0f) ? g.w : 0.0f);
                float wt = wx * wy;
                if (wt > 0.0f) {
                    float4 v = vw[d][qly + oy][qlx + ox];
                    acc[d][0] += wt * v.x;
                    acc[d][1] += wt * v.y;
                    acc[d][2] += wt * v.z;
                    acc[d][3] += wt * v.w;
                }
            }
        }
    }

    // ---- flush: each thread owns exactly one output pixel -> plain stores ----
    const size_t q = (size_t)(tY0 + qly) * Ww + (tX0 + qlx);
    bool flagged = true;
    if (flags)
        flagged = flags[(b * TILES_Y + tY) * TILES_X + tX] != 0;

#pragma unroll
    for (int d = 0; d < 2; ++d) {
        float* accImg = out + ((size_t)b * OUTC + (d ? 9 : 6)) * HW;
        float* accW   = out + ((size_t)b * OUTC + (d ? 17 : 16)) * HW;
        float s0 = acc[d][0];
        float s1 = acc[d][1];
        float s2 = acc[d][2];
        float sw = acc[d][3];
        if (flagged) {            // rare: merge prepass far contributions
            s0 += accImg[q];
            s1 += accImg[HW + q];
            s2 += accImg[2 * HW + q];
            sw += accW[q];
        }
        float inv = 1.0f / (sw + EPSF);
        accImg[q]          = s0 * inv;   // normalized f01i / f10i
        accImg[HW + q]     = s1 * inv;
        accImg[2 * HW + q] = s2 * inv;
        accW[q]            = sw;         // raw weight sum for erode
    }
}

// ---------------------------------------------------------------------------
// Erosion of raw weight sums ch16/17 -> er planes (ws or ch12/13).
// k<=5: LDS-tiled separable (row-min + col-min, clamped staging is exact).
// k>5: legacy per-pixel full window (grid is identically Bb*HW/256 blocks).
// k<=0: copy.
// ---------------------------------------------------------------------------
__global__ __launch_bounds__(256) void erode5_kernel(float* out, float* erbuf,
                                                     int er_in_out,
                                                     const int* __restrict__ kptr)
{
    __shared__ float s2  [2][EH][EW];
    __shared__ float rmin[2][EH][OWN_W];

    int k = *kptr;

    if (k > 5) {   // legacy fallback path (merged kernel)
        int i = blockIdx.x * 256 + threadIdx.x;
        int b = i / HW;
        int p = i - b * HW;
        int y = p / Ww;
        int x = p - y * Ww;
        const float* s01 = out + ((size_t)b * OUTC + 16) * HW;
        const float* s10 = out + ((size_t)b * OUTC + 17) * HW;
        float* er01 = er_in_out ? out + ((size_t)b * OUTC + 12) * HW : erbuf + ((size_t)b * 2 + 0) * HW;
        float* er10 = er_in_out ? out + ((size_t)b * OUTC + 13) * HW : erbuf + ((size_t)b * 2 + 1) * HW;
        int lo = (k - 1) / 2, hi = (k - 1) - lo;
        float m0 = INFINITY, m1 = INFINITY;
        for (int dy = -lo; dy <= hi; ++dy) {
            int yy = y + dy;
            if (yy < 0 || yy >= Hh) continue;
            for (int dx = -lo; dx <= hi; ++dx) {
                int xx = x + dx;
                if (xx < 0 || xx >= Ww) continue;
                int q = yy * Ww + xx;
                m0 = fminf(m0, s01[q]);
                m1 = fminf(m1, s10[q]);
            }
        }
        er01[p] = m0;
        er10[p] = m1;
        return;
    }

    int wg   = blockIdx.x;
    int wgid = (wg & 7) * (NTILES / 8) + (wg >> 3);
    int b    = wgid / (TILES_X * TILES_Y);
    int rr   = wgid - b * (TILES_X * TILES_Y);
    int tY   = rr / TILES_X;
    int tX   = rr - tY * TILES_X;
    const int tX0 = tX * OWN_W;
    const int tY0 = tY * OWN_H;

    const float* s01 = out + ((size_t)b * OUTC + 16) * HW;
    const float* s10 = out + ((size_t)b * OUTC + 17) * HW;
    float* er01 = er_in_out ? out + ((size_t)b * OUTC + 12) * HW : erbuf + ((size_t)b * 2 + 0) * HW;
    float* er10 = er_in_out ? out + ((size_t)b * OUTC + 13) * HW : erbuf + ((size_t)b * 2 + 1) * HW;

    const int r  = threadIdx.x >> 5;
    const int xc = threadIdx.x & 31;
    const size_t qp = (size_t)(tY0 + r) * Ww + (tX0 + xc);

    if (k <= 0) { er01[qp] = s01[qp]; er10[qp] = s10[qp]; return; }

    const int lo = (k - 1) / 2;
    const int ew = OWN_W + k - 1;    // <= 36
    const int eh = OWN_H + k - 1;    // <= 12

    for (int c = threadIdx.x; c < eh * ew; c += 256) {
        int i = c / ew, j = c - i * ew;
        int gy = min(max(tY0 - lo + i, 0), Hh - 1);
        int gx = min(max(tX0 - lo + j, 0), Ww - 1);
        size_t p = (size_t)gy * Ww + gx;
        s2[0][i][j] = s01[p];
        s2[1][i][j] = s10[p];
    }
    __syncthreads();

    for (int c = threadIdx.x; c < eh * OWN_W; c += 256) {
        int i = c / OWN_W, x = c - i * OWN_W;
        float m0 = s2[0][i][x], m1 = s2[1][i][x];
        for (int t = 1; t < k; ++t) {
            m0 = fminf(m0, s2[0][i][x + t]);
            m1 = fminf(m1, s2[1][i][x + t]);
        }
        rmin[0][i][x] = m0;
        rmin[1][i][x] = m1;
    }
    __syncthreads();

    float m0 = rmin[0][r][xc], m1 = rmin[1][r][xc];
    for (int t = 1; t < k; ++t) {
        m0 = fminf(m0, rmin[0][r + t][xc]);
        m1 = fminf(m1, rmin[1][r + t][xc]);
    }
    er01[qp] = m0;
    er10[qp] = m1;
}

// ---------------------------------------------------------------------------
// Dilation of er planes + mask + blend. k<=5: LDS-tiled separable.
// k>5: legacy per-pixel. Writes ch0..5, 16, 17.
// ---------------------------------------------------------------------------
__global__ __launch_bounds__(256) void fuse5_kernel(float* out, const float* erbuf,
                                                    int er_in_out,
                                                    const int* __restrict__ kptr)
{
    __shared__ float e2  [2][EH][EW];
    __shared__ float rmax[2][EH][OWN_W];

    int k = *kptr;

    if (k > 5) {   // legacy fallback path (merged kernel)
        int i = blockIdx.x * 256 + threadIdx.x;
        int b = i / HW;
        int p = i - b * HW;
        int y = p / Ww;
        int x = p - y * Ww;
        const float* er01 = er_in_out ? out + ((size_t)b * OUTC + 12) * HW : erbuf + ((size_t)b * 2 + 0) * HW;
        const float* er10 = er_in_out ? out + ((size_t)b * OUTC + 13) * HW : erbuf + ((size_t)b * 2 + 1) * HW;
        int lo = (k - 1) / 2, hi = (k - 1) - lo;
        float o0 = -INFINITY, o1 = -INFINITY;
        for (int dy = -lo; dy <= hi; ++dy) {
            int yy = y + dy;
            if (yy < 0 || yy >= Hh) continue;
            for (int dx = -lo; dx <= hi; ++dx) {
                int xx = x + dx;
                if (xx < 0 || xx >= Ww) continue;
                int q = yy * Ww + xx;
                o0 = fmaxf(o0, er01[q]);
                o1 = fmaxf(o1, er10[q]);
            }
        }
        float m01 = o0 / (o0 + EPSF);
        float m10 = o1 / (o1 + EPSF);
        float* ob = out + (size_t)b * OUTC * HW;
#pragma unroll
        for (int c = 0; c < 3; ++c) {
            float f01i = ob[((size_t)6 + c) * HW + p];
            float f10i = ob[((size_t)9 + c) * HW + p];
            ob[((size_t)0 + c) * HW + p] = m01 * f01i + (1.0f - m01) * f10i;
            ob[((size_t)3 + c) * HW + p] = m10 * f10i + (1.0f - m10) * f01i;
        }
        ob[(size_t)16 * HW + p] = m01;
        ob[(size_t)17 * HW + p] = m10;
        return;
    }

    int wg   = blockIdx.x;
    int wgid = (wg & 7) * (NTILES / 8) + (wg >> 3);
    int b    = wgid / (TILES_X * TILES_Y);
    int rr   = wgid - b * (TILES_X * TILES_Y);
    int tY   = rr / TILES_X;
    int tX   = rr - tY * TILES_X;
    const int tX0 = tX * OWN_W;
    const int tY0 = tY * OWN_H;

    const float* er01 = er_in_out ? out + ((size_t)b * OUTC + 12) * HW : erbuf + ((size_t)b * 2 + 0) * HW;
    const float* er10 = er_in_out ? out + ((size_t)b * OUTC + 13) * HW : erbuf + ((size_t)b * 2 + 1) * HW;

    const int r  = threadIdx.x >> 5;
    const int xc = threadIdx.x & 31;
    const size_t qp = (size_t)(tY0 + r) * Ww + (tX0 + xc);

    float o0, o1;
    if (k <= 0) {
        o0 = er01[qp];
        o1 = er10[qp];
    } else {
        const int lo = (k - 1) / 2;
        const int ew = OWN_W + k - 1;
        const int eh = OWN_H + k - 1;

        for (int c = threadIdx.x; c < eh * ew; c += 256) {
            int i = c / ew, j = c - i * ew;
            int gy = min(max(tY0 - lo + i, 0), Hh - 1);
            int gx = min(max(tX0 - lo + j, 0), Ww - 1);
            size_t p = (size_t)gy * Ww + gx;
            e2[0][i][j] = er01[p];
            e2[1][i][j] = er10[p];
        }
        __syncthreads();

        for (int c = threadIdx.x; c < eh * OWN_W; c += 256) {
            int i = c / OWN_W, x = c - i * OWN_W;
            float m0 = e2[0][i][x], m1 = e2[1][i][x];
            for (int t = 1; t < k; ++t) {
                m0 = fmaxf(m0, e2[0][i][x + t]);
                m1 = fmaxf(m1, e2[1][i][x + t]);
            }
            rmax[0][i][x] = m0;
            rmax[1][i][x] = m1;
        }
        __syncthreads();

        o0 = rmax[0][r][xc]; o1 = rmax[1][r][xc];
        for (int t = 1; t < k; ++t) {
            o0 = fmaxf(o0, rmax[0][r + t][xc]);
            o1 = fmaxf(o1, rmax[1][r + t][xc]);
        }
    }

    float m01 = o0 / (o0 + EPSF);
    float m10 = o1 / (o1 + EPSF);

    float* ob = out + (size_t)b * OUTC * HW;
#pragma unroll
    for (int c = 0; c < 3; ++c) {
        float f01i = ob[((size_t)6 + c) * HW + qp];   // already normalized by gather
        float f10i = ob[((size_t)9 + c) * HW + qp];
        ob[((size_t)0 + c) * HW + qp] = m01 * f01i + (1.0f - m01) * f10i;
        ob[((size_t)3 + c) * HW + qp] = m10 * f10i + (1.0f - m10) * f01i;
    }
    ob[(size_t)16 * HW + qp] = m01;
    ob[(size_t)17 * HW + qp] = m10;
}

// ---------------------------------------------------------------------------
// Fallback only (no ws): write 0.5*flow0 into ch12/13 after fuse. Last.
// ---------------------------------------------------------------------------
__global__ __launch_bounds__(256) void flow_kernel(const float* __restrict__ flow0,
                                                   float* __restrict__ out)
{
    int i = blockIdx.x * 256 + threadIdx.x;
    if (i >= Bb * 2 * HW) return;
    int b = i / (2 * HW);
    int r = i - b * 2 * HW;
    int c = r / HW;
    int p = r - c * HW;
    out[((size_t)b * OUTC + 12 + c) * HW + p] = 0.5f * flow0[((size_t)b * 2 + c) * HW + p];
}

extern "C" void kernel_launch(void* const* d_in, const int* in_sizes, int n_in,
                              void* d_out, int out_size, void* d_ws, size_t ws_size,
                              hipStream_t stream) {
    const float* img0  = (const float*)d_in[0];
    const float* img1  = (const float*)d_in[1];
    const float* flow0 = (const float*)d_in[2];
    const float* flow1 = (const float*)d_in[3];
    const float* z0    = (const float*)d_in[4];
    const float* z1    = (const float*)d_in[5];
    const int*   kptr  = (const int*)d_in[6];
    float* out = (float*)d_out;

    const size_t flagsBytes = (((size_t)NTILES * sizeof(int)) + 255) & ~(size_t)255;
    const size_t erBytes    = (size_t)Bb * 2 * HW * sizeof(float);

    int*   flags = (d_ws && ws_size >= (size_t)NTILES * sizeof(int)) ? (int*)d_ws : nullptr;
    bool   wsmode = d_ws && ws_size >= flagsBytes + erBytes;
    float* erbuf  = wsmode ? (float*)((char*)d_ws + flagsBytes) : nullptr;
    int    er_in_out = wsmode ? 0 : 1;   // fallback: park erosion in ch12/13

    zero_kernel<<<2048, 256, 0, stream>>>(out, flags);
    far_prepass_kernel<<<NTILES, 256, 0, stream>>>(img0, img1, flow0, flow1, z0, z1,
                                                   out, flags, wsmode ? 1 : 0);
    gather_splat_kernel<<<NTILES, 256, 0, stream>>>(img0, img1, flow0, flow1, z0, z1, out, flags);
    erode5_kernel<<<NTILES, 256, 0, stream>>>(out, erbuf, er_in_out, kptr);
    fuse5_kernel<<<NTILES, 256, 0, stream>>>(out, erbuf, er_in_out, kptr);
    if (!wsmode) {
        int n2 = Bb * 2 * HW;
        flow_kernel<<<(n2 + 255) / 256, 256, 0, stream>>>(flow0, out);
    }
}